// Round 8
// baseline (397.182 us; speedup 1.0000x reference)
//
#include <hip/hip_runtime.h>
#include <hip/hip_fp16.h>
#include <math.h>

#define CDIV(a, b) (((a) + (b) - 1) / (b))
#define SCAN_BS 1024
#define NBUK 512          // dst buckets (dst>>7); covers N <= 65536
#define ATILE 4096        // edges per Stage-A block

typedef _Float16 f16x8 __attribute__((ext_vector_type(8)));
typedef float f32x4 __attribute__((ext_vector_type(4)));

// ---------- float <-> monotone-unsigned encoding for atomicMax on floats ----
__device__ __forceinline__ unsigned encf(float v) {
    unsigned u = __float_as_uint(v);
    return (u & 0x80000000u) ? ~u : (u | 0x80000000u);
}
__device__ __forceinline__ float decf(unsigned k) {
    unsigned u = (k & 0x80000000u) ? (k ^ 0x80000000u) : ~k;
    return __uint_as_float(u);
}

__device__ __forceinline__ float lrelu(float v) {
    return v > 0.f ? v : 0.2f * v;
}

// ---------- naive GEMM fallback (only if shapes are unexpected) -------------
__global__ __launch_bounds__(256) void gemm_kernel(
    const float* __restrict__ X, const float* __restrict__ W,
    float* __restrict__ Y, int M, int K, int Nout) {
    int idx = blockIdx.x * blockDim.x + threadIdx.x;
    if (idx >= M * Nout) return;
    int row = idx / Nout;
    int col = idx - row * Nout;
    const float* xr = X + (size_t)row * K;
    const float* wc = W + col;
    float acc = 0.f;
    for (int k = 0; k < K; k += 4) {
        float4 xv = *(const float4*)(xr + k);
        acc += xv.x * wc[(size_t)(k + 0) * Nout];
        acc += xv.y * wc[(size_t)(k + 1) * Nout];
        acc += xv.z * wc[(size_t)(k + 2) * Nout];
        acc += xv.w * wc[(size_t)(k + 3) * Nout];
    }
    Y[idx] = acc;
}

// ---------- weight prep: swizzle W (K x NOUT fp32) into B-fragment order ----
__device__ __forceinline__ void wprep_one(const float* __restrict__ W,
                                          __half* __restrict__ Whf, int K,
                                          int NOUT, int idx) {
    int NK = K / 32;
    int l = idx & 63, f = idx >> 6;
    int ks = f % NK, tt = f / NK;
    int quad = l >> 4, c15 = l & 15;
    _Float16 v[8];
#pragma unroll
    for (int j = 0; j < 8; ++j) {
        int k = ks * 32 + quad * 8 + j;
        int n = tt * 16 + c15;
        v[j] = (_Float16)W[(size_t)k * NOUT + n];
    }
    *(uint4*)(Whf + (size_t)idx * 8) = *(uint4*)v;
}

// LDS-destination variant (same math; generic-pointer store works for LDS)
__device__ __forceinline__ void wprep_one_lds(const float* __restrict__ W,
                                              __half* Whf, int K, int NOUT,
                                              int idx) {
    int NK = K / 32;
    int l = idx & 63, f = idx >> 6;
    int ks = f % NK, tt = f / NK;
    int quad = l >> 4, c15 = l & 15;
    _Float16 v[8];
#pragma unroll
    for (int j = 0; j < 8; ++j) {
        int k = ks * 32 + quad * 8 + j;
        int n = tt * 16 + c15;
        v[j] = (_Float16)W[(size_t)k * NOUT + n];
    }
    *(uint4*)(Whf + (size_t)idx * 8) = *(uint4*)v;
}

// ---------- A-fragment loaders ----------------------------------------------
__device__ __forceinline__ f16x8 loadA(const float* p) {
    float4 lo = *(const float4*)p;
    float4 hi = *(const float4*)(p + 4);
    f16x8 a;
    a[0] = (_Float16)lo.x; a[1] = (_Float16)lo.y;
    a[2] = (_Float16)lo.z; a[3] = (_Float16)lo.w;
    a[4] = (_Float16)hi.x; a[5] = (_Float16)hi.y;
    a[6] = (_Float16)hi.z; a[7] = (_Float16)hi.w;
    return a;
}
__device__ __forceinline__ f16x8 loadA(const __half* p) {
    return *(const f16x8*)p;
}

// ---------- MFMA GEMM + fused attention-coefficient epilogue (body) ---------
// Y[M,NOUT] (fp16) = X[M,K] @ B-fragments bp; es/ed[M,HH] from the fp32
// accumulators (head h covers channels [32h,32h+32) = tiles 2h,2h+1).
template <int K, int NOUT, int HH, typename XT, typename BP>
__device__ __forceinline__ void gemm_attn_body(
    const XT* __restrict__ X, const BP* bp, __half* __restrict__ Y,
    const float* __restrict__ a_src, const float* __restrict__ a_dst,
    float* __restrict__ es, float* __restrict__ ed, int M, int blk) {
    constexpr int NK = K / 32, NT = NOUT / 16;
    static_assert(NT == 2 * HH, "32 channels per head assumed");
    int wave = threadIdx.x >> 6, lane = threadIdx.x & 63;
    int quad = lane >> 4, c15 = lane & 15;
    int row0 = (blk * 4 + wave) * 16;
    if (row0 >= M) return;  // uniform per wave
    int arow = row0 + c15;
    if (arow >= M) arow = M - 1;
    const XT* xr = X + (size_t)arow * K + quad * 8;
    f32x4 acc[NT];
#pragma unroll
    for (int t = 0; t < NT; ++t) {
        acc[t][0] = 0.f; acc[t][1] = 0.f; acc[t][2] = 0.f; acc[t][3] = 0.f;
    }
#pragma unroll
    for (int ks = 0; ks < NK; ++ks) {
        f16x8 a = loadA(xr + ks * 32);
#pragma unroll
        for (int t = 0; t < NT; ++t) {
            f16x8 b = *(const f16x8*)&bp[((t * NK + ks) * 64 + lane) * 8];
            acc[t] = __builtin_amdgcn_mfma_f32_16x16x32_f16(a, b, acc[t],
                                                            0, 0, 0);
        }
    }
    // store Y (C/D mapping: row = quad*4+r, col = t*16+c15)
#pragma unroll
    for (int r = 0; r < 4; ++r) {
        int row = row0 + quad * 4 + r;
        if (row < M) {
#pragma unroll
            for (int t = 0; t < NT; ++t)
                Y[(size_t)row * NOUT + t * 16 + c15] = (__half)acc[t][r];
        }
    }
    // attention epilogue: es[row,h] = sum_c Y[row,32h+c]*a_src[32h+c]
    float asv[NT], adv[NT];
#pragma unroll
    for (int t = 0; t < NT; ++t) {
        asv[t] = a_src[t * 16 + c15];
        adv[t] = a_dst[t * 16 + c15];
    }
#pragma unroll
    for (int h = 0; h < HH; ++h) {
#pragma unroll
        for (int r = 0; r < 4; ++r) {
            float s = acc[2 * h][r] * asv[2 * h] +
                      acc[2 * h + 1][r] * asv[2 * h + 1];
            float dd = acc[2 * h][r] * adv[2 * h] +
                       acc[2 * h + 1][r] * adv[2 * h + 1];
#pragma unroll
            for (int off = 8; off >= 1; off >>= 1) {
                s += __shfl_xor(s, off);     // stays inside the 16-lane quad
                dd += __shfl_xor(dd, off);
            }
            int row = row0 + quad * 4 + r;
            if (row < M) {
                if (c15 == 0) es[row * HH + h] = s;
                if (c15 == 1) ed[row * HH + h] = dd;
            }
        }
    }
}

// ============ Bucketed CSR build ============================================
// Stage A1: per-block bucket histogram (bucket = dst>>7). Side jobs folded in:
//   - zero-fills the pooling buffers (replaces 3 hipMemsetAsync dispatches)
//   - blocks [nhist, nhist+nwp): wh2/wh3 weight swizzles + rowptr[N] sentinel
//   - blocks >= nhist+nwp: layer-1 GEMM+attn with inline W1->LDS swizzle
//     (gemm1 has no CSR dependency; overlaps with the histogram phase)
__global__ __launch_bounds__(256) void binA1_kernel(
    const int* __restrict__ ei, int E, int* __restrict__ ghist,
    int* __restrict__ pool0, int poolN, const float* __restrict__ W1,
    const float* __restrict__ W2, const float* __restrict__ W3,
    __half* __restrict__ wh2, __half* __restrict__ wh3,
    int* __restrict__ rowptr, int N, int nhist, int nwp,
    const float* __restrict__ x, __half* __restrict__ Qh,
    const float* __restrict__ as1, const float* __restrict__ ad1,
    float* __restrict__ es, float* __restrict__ ed) {
    __shared__ int lh[NBUK];
    __shared__ __half wlds[512 * 8];   // 8 KB: W1 fragments for gemm1 blocks
    int t = threadIdx.x;
    if (blockIdx.x >= nhist + nwp) {   // ---- gemm1 blocks ----
        for (int i = t; i < 512; i += 256)
            wprep_one_lds(W1, wlds, 32, 128, i);
        __syncthreads();
        gemm_attn_body<32, 128, 4>(x, wlds, Qh, as1, ad1, es, ed, N,
                                   blockIdx.x - nhist - nwp);
        return;
    }
    if (blockIdx.x >= nhist) {         // ---- weight-prep blocks (wh2/wh3) --
        int idx = (blockIdx.x - nhist) * 256 + t;
        if (idx == 0) rowptr[N] = E + N;
        if (idx < 2048) {
            wprep_one(W2, wh2, 128, 128, idx);         // 8*4*64 = 2048
        } else if (idx < 2560) {
            wprep_one(W3, wh3, 128, 32, idx - 2048);   // 2*4*64 = 512
        }
        return;
    }
    int gid = blockIdx.x * 256 + t;
    if (gid < poolN) pool0[gid] = 0;
    for (int i = t; i < NBUK; i += 256) lh[i] = 0;
    __syncthreads();
    int base = blockIdx.x * ATILE;
#pragma unroll 4
    for (int j = 0; j < ATILE / 256; ++j) {
        int idx = base + t + 256 * j;
        if (idx < E) atomicAdd(&lh[ei[E + idx] >> 7], 1);
    }
    __syncthreads();
    int* gh = ghist + (size_t)blockIdx.x * NBUK;
    for (int i = t; i < NBUK; i += 256) gh[i] = lh[i];
}

// Stage A2: one wave per bucket — exclusive prefix over blocks (column scan)
__global__ __launch_bounds__(64) void binA2a_kernel(
    int* __restrict__ ghist, int* __restrict__ tot, int nblk) {
    int b = blockIdx.x;
    int lane = threadIdx.x;
    int accb = 0;
    for (int chunk = 0; chunk < nblk; chunk += 64) {
        int i = chunk + lane;
        int v = (i < nblk) ? ghist[(size_t)i * NBUK + b] : 0;
        int s = v;
        for (int off = 1; off < 64; off <<= 1) {
            int tv = __shfl_up(s, off);
            if (lane >= off) s += tv;
        }
        if (i < nblk) ghist[(size_t)i * NBUK + b] = s - v + accb;  // exclusive
        accb += __shfl(s, 63);
    }
    if (lane == 0) tot[b] = accb;
}

// in-block exclusive scan over tot[NBUK] (256 threads, 2 elems each).
// On return: excl = prefix of element 2t; a0/a1 = tot[2t], tot[2t+1].
__device__ __forceinline__ void bucketScan(const int* __restrict__ tot,
                                           int* __restrict__ sc, int t,
                                           int& a0, int& a1, int& excl) {
    a0 = tot[2 * t];
    a1 = tot[2 * t + 1];
    int pair = a0 + a1;
    sc[t] = pair;
    __syncthreads();
#pragma unroll
    for (int off = 1; off < 256; off <<= 1) {
        int v = (t >= off) ? sc[t - off] : 0;
        __syncthreads();
        sc[t] += v;
        __syncthreads();
    }
    excl = sc[t] - pair;
}

// Stage A3: binned scatter of packed (dst<<16)|src into bucket-contiguous ebuf
// (bucket base offsets recomputed in-block from tot — no binA2b dispatch).
__global__ __launch_bounds__(256) void binA3_kernel(
    const int* __restrict__ ei, int E, const int* __restrict__ ghist,
    const int* __restrict__ tot, unsigned* __restrict__ ebuf) {
    __shared__ int lcur[NBUK];
    __shared__ int sc[256];
    int t = threadIdx.x;
    int a0, a1, excl;
    bucketScan(tot, sc, t, a0, a1, excl);
    const int* gh = ghist + (size_t)blockIdx.x * NBUK;
    lcur[2 * t] = gh[2 * t] + excl;
    lcur[2 * t + 1] = gh[2 * t + 1] + excl + a0;
    __syncthreads();
    int base = blockIdx.x * ATILE;
#pragma unroll 4
    for (int j = 0; j < ATILE / 256; ++j) {
        int idx = base + t + 256 * j;
        if (idx < E) {
            int s = ei[idx];
            int d = ei[E + idx];
            int pos = atomicAdd(&lcur[d >> 7], 1);
            ebuf[pos] = ((unsigned)d << 16) | (unsigned)s;
        }
    }
}

// Stage B: one block per bucket — local degree histogram + prefix gives
// rowptr (contiguous write) and the final CSR scatter into this bucket's
// private csrc region. Bucket range recomputed in-block from tot.
__global__ __launch_bounds__(256) void binB_kernel(
    const unsigned* __restrict__ ebuf, const int* __restrict__ tot,
    int* __restrict__ rowptr, int* __restrict__ csrc, int N) {
    __shared__ int cnt_[128];
    __shared__ int pre[128];
    __shared__ int lcur[128];
    __shared__ int sc[256];
    __shared__ int begS;
    int b = blockIdx.x;
    int t = threadIdx.x;
    int n0 = b << 7;
    int totb = tot[b];
    if (t < 128) cnt_[t] = 0;
    int a0, a1, excl;
    bucketScan(tot, sc, t, a0, a1, excl);
    if (t == (b >> 1)) begS = (b & 1) ? (excl + a0) : excl;
    __syncthreads();
    int beg = begS, end = begS + totb;
    for (int i = beg + t; i < end; i += 256)
        atomicAdd(&cnt_[(ebuf[i] >> 16) - n0], 1);
    __syncthreads();
    // inclusive scan of (cnt+1 if node valid else 0) over 128 entries
    if (t < 128) pre[t] = (n0 + t < N) ? (cnt_[t] + 1) : 0;
    __syncthreads();
    for (int off = 1; off < 128; off <<= 1) {
        int v = 0;
        if (t < 128 && t >= off) v = pre[t - off];
        __syncthreads();
        if (t < 128) pre[t] += v;
        __syncthreads();
    }
    int cbase = beg + n0;  // edges before bucket + self-loop slots before it
    if (t < 128 && n0 + t < N) {
        int ex = pre[t] - (cnt_[t] + 1);
        int rp = cbase + ex;
        rowptr[n0 + t] = rp;
        csrc[rp] = n0 + t;   // self-loop in slot 0
        lcur[t] = rp + 1;
    }
    __syncthreads();
    for (int i = beg + t; i < end; i += 256) {
        unsigned e = ebuf[i];
        int d = (int)(e >> 16) - n0;
        int s = (int)(e & 0xFFFFu);
        int pos = atomicAdd(&lcur[d], 1);
        csrc[pos] = s;
    }
}

// ---------- attention coefficients (fallback path, fp32) --------------------
__global__ __launch_bounds__(256) void attn_kernel(
    const float* __restrict__ h, const float* __restrict__ a_src,
    const float* __restrict__ a_dst, float* __restrict__ es,
    float* __restrict__ ed, int N, int H, int C) {
    int idx = blockIdx.x * blockDim.x + threadIdx.x;
    if (idx >= N * H) return;
    int n = idx / H;
    int hh = idx - n * H;
    const float* hp = h + (size_t)n * H * C + (size_t)hh * C;
    const float* ap = a_src + hh * C;
    const float* bp = a_dst + hh * C;
    float s = 0.f, d = 0.f;
    for (int c = 0; c < C; c += 4) {
        float4 hv = *(const float4*)(hp + c);
        float4 av = *(const float4*)(ap + c);
        float4 bv = *(const float4*)(bp + c);
        s += hv.x * av.x + hv.y * av.y + hv.z * av.z + hv.w * av.w;
        d += hv.x * bv.x + hv.y * bv.y + hv.z * bv.z + hv.w * bv.w;
    }
    es[idx] = s;
    ed[idx] = d;
}

// ---------- fallback CSR build (generic shapes) -----------------------------
__global__ __launch_bounds__(256) void deg_kernel(const int* __restrict__ ei,
                                                  int E,
                                                  int* __restrict__ deg) {
    int e = blockIdx.x * blockDim.x + threadIdx.x;
    if (e >= E) return;
    atomicAdd(&deg[ei[E + e]], 1);
}

__global__ __launch_bounds__(SCAN_BS) void scan1_kernel(
    const int* __restrict__ deg, int* __restrict__ rowptr,
    int* __restrict__ bsum, int N) {
    __shared__ int tmp[SCAN_BS];
    int tid = threadIdx.x;
    int gid = blockIdx.x * SCAN_BS + tid;
    int v = (gid < N) ? (deg[gid] + 1) : 0;
    tmp[tid] = v;
    __syncthreads();
    for (int off = 1; off < SCAN_BS; off <<= 1) {
        int t = (tid >= off) ? tmp[tid - off] : 0;
        __syncthreads();
        tmp[tid] += t;
        __syncthreads();
    }
    if (gid < N) rowptr[gid] = tmp[tid] - v;
    if (tid == SCAN_BS - 1) bsum[blockIdx.x] = tmp[tid];
}

__global__ void scan2_kernel(int* __restrict__ bsum, int nb) {
    if (threadIdx.x == 0 && blockIdx.x == 0) {
        int acc = 0;
        for (int i = 0; i < nb; ++i) {
            int t = bsum[i];
            bsum[i] = acc;
            acc += t;
        }
    }
}

__global__ __launch_bounds__(SCAN_BS) void scan3_kernel(
    int* __restrict__ rowptr, int* __restrict__ cursor,
    int* __restrict__ csrc, const int* __restrict__ bsum, int N, int total) {
    int gid = blockIdx.x * SCAN_BS + threadIdx.x;
    if (gid < N) {
        int v = rowptr[gid] + bsum[blockIdx.x];
        rowptr[gid] = v;
        cursor[gid] = v + 1;
        csrc[v] = gid;
    }
    if (gid == 0) rowptr[N] = total;
}

__global__ __launch_bounds__(256) void scatter_kernel(
    const int* __restrict__ ei, int E, int* __restrict__ cursor,
    int* __restrict__ csrc) {
    int e = blockIdx.x * blockDim.x + threadIdx.x;
    if (e >= E) return;
    int s = ei[e];
    int d = ei[E + e];
    int pos = atomicAdd(&cursor[d], 1);
    csrc[pos] = s;
}

// ====== FUSED: softmax-aggregate + bias + LN + ELU -> LDS -> next GEMM ======
// Phase 1 (WORK-STEALING): the block's 16 dsts' edge lists are cut into
// 8-edge chunks; the 16 lane-groups grab chunks from an LDS queue (leader
// atomicAdd + intra-group shfl broadcast), accumulate each chunk privately
// in registers (same batched gather as the verified walk), and commit via
// LDS float atomics. Removes the max-degree straggler at the barrier.
// Phase 2: the block's 16 rows are one MFMA A-tile; 4 waves run
// Y[16,NOUT] = lds @ Whf + attention epilogue.
template <int NOUT, int HH>
__global__ __launch_bounds__(256) void aggr_gemm_kernel(
    const int* __restrict__ rowptr, const int* __restrict__ csrc,
    const __half* __restrict__ h, const float* __restrict__ es,
    const float* __restrict__ ed, const float* __restrict__ bias,
    const float* __restrict__ gam, const float* __restrict__ bet,
    const __half* __restrict__ Whf, __half* __restrict__ Y,
    const float* __restrict__ a_src, const float* __restrict__ a_dst,
    float* __restrict__ es_o, float* __restrict__ ed_o, int N) {
    constexpr int D = 128, H = 4;          // aggregation-side geometry
    constexpr int NK = 4, NT = NOUT / 16;  // GEMM K = 128
    static_assert(NT == 2 * HH, "32 channels per head assumed");
    __shared__ float accS[16][132];        // per-dst accum (+4-word pad)
    __shared__ float lsumS[16][4];         // per (dst, head) denominators
    __shared__ __half ldsA[16][136];       // LN output tile (MFMA A operand)
    __shared__ int begS[16], endS[16], chunkBase[17];
    __shared__ int qctr;
    int tid = threadIdx.x;
    int r = tid >> 4;                      // group / block-local row 0..15
    int cl = tid & 15;
    int c = cl * 8;                        // 8 consecutive channels
    int hh = cl >> 2;                      // head = c/32
    int d0 = blockIdx.x * 16;
    // -------- init --------
    for (int i = tid; i < 16 * 132; i += 256) ((float*)accS)[i] = 0.f;
    if (tid < 64) lsumS[tid >> 2][tid & 3] = 0.f;
    if (tid < 16) {
        int dd = d0 + tid;
        begS[tid] = (dd < N) ? rowptr[dd] : 0;
        endS[tid] = (dd < N) ? rowptr[dd + 1] : 0;
    }
    if (tid == 0) qctr = 0;
    __syncthreads();
    if (tid == 0) {
        int a = 0;
        for (int i = 0; i < 16; ++i) {
            chunkBase[i] = a;
            a += (endS[i] - begS[i] + 7) >> 3;
        }
        chunkBase[16] = a;
    }
    __syncthreads();
    int T = chunkBase[16];
    int gleader = (tid & 63) & ~15;        // wave-lane of group leader
    // -------- phase 1: work-stealing chunk loop --------
    while (true) {
        int ci = 0;
        if (cl == 0) ci = atomicAdd(&qctr, 1);
        ci = __shfl(ci, gleader);
        if (ci >= T) break;
        int ld = 0;
        while (chunkBase[ld + 1] <= ci) ++ld;
        int dd = d0 + ld;
        float edv = ed[dd * H + hh];
        int kb = begS[ld] + ((ci - chunkBase[ld]) << 3);
        int ke = endS[ld];
        int s[8];
#pragma unroll
        for (int j = 0; j < 8; ++j) {
            int kk = kb + j;
            s[j] = csrc[kk < ke ? kk : kb];
        }
        float e[8];
#pragma unroll
        for (int j = 0; j < 8; ++j) e[j] = es[s[j] * H + hh];
        uint4 u[8];
#pragma unroll
        for (int j = 0; j < 8; ++j)
            u[j] = *(const uint4*)(h + (size_t)s[j] * D + c);
        float a[8];
#pragma unroll
        for (int i = 0; i < 8; ++i) a[i] = 0.f;
        float lp = 0.f;
#pragma unroll
        for (int j = 0; j < 8; ++j) {
            float w = (kb + j < ke) ? __expf(lrelu(e[j] + edv)) : 0.f;
            lp += w;
            const __half2* hp = (const __half2*)&u[j];
#pragma unroll
            for (int i = 0; i < 4; ++i) {
                float2 f = __half22float2(hp[i]);
                a[2 * i] += w * f.x;
                a[2 * i + 1] += w * f.y;
            }
        }
#pragma unroll
        for (int i = 0; i < 8; ++i) atomicAdd(&accS[ld][c + i], a[i]);
        if ((cl & 3) == 0) atomicAdd(&lsumS[ld][hh], lp);
    }
    __syncthreads();
    // -------- LN + ELU -> LDS tile --------
    int d = d0 + r;
    if (d < N) {
        float l = lsumS[r][hh];
        float rl = 1.f / (l + 1e-16f);
        float4 b0 = *(const float4*)(bias + c);
        float4 b1 = *(const float4*)(bias + c + 4);
        float v[8];
        v[0] = accS[r][c + 0] * rl + b0.x;
        v[1] = accS[r][c + 1] * rl + b0.y;
        v[2] = accS[r][c + 2] * rl + b0.z;
        v[3] = accS[r][c + 3] * rl + b0.w;
        v[4] = accS[r][c + 4] * rl + b1.x;
        v[5] = accS[r][c + 5] * rl + b1.y;
        v[6] = accS[r][c + 6] * rl + b1.z;
        v[7] = accS[r][c + 7] * rl + b1.w;
        float sm = 0.f, ssum = 0.f;
#pragma unroll
        for (int i = 0; i < 8; ++i) { sm += v[i]; ssum += v[i] * v[i]; }
#pragma unroll
        for (int off = 1; off <= 8; off <<= 1) {   // 16-lane group reduce
            sm += __shfl_xor(sm, off);
            ssum += __shfl_xor(ssum, off);
        }
        float mean = sm / D;
        float var = ssum / D - mean * mean;
        float rstd = rsqrtf(var + 1e-5f);
        float4 g0 = *(const float4*)(gam + c);
        float4 g1 = *(const float4*)(gam + c + 4);
        float4 t0 = *(const float4*)(bet + c);
        float4 t1 = *(const float4*)(bet + c + 4);
        float gv[8] = {g0.x, g0.y, g0.z, g0.w, g1.x, g1.y, g1.z, g1.w};
        float tv[8] = {t0.x, t0.y, t0.z, t0.w, t1.x, t1.y, t1.z, t1.w};
        __half2 p[4];
#pragma unroll
        for (int i = 0; i < 4; ++i) {
            float o0 = (v[2 * i] - mean) * rstd * gv[2 * i] + tv[2 * i];
            float o1 = (v[2 * i + 1] - mean) * rstd * gv[2 * i + 1] +
                       tv[2 * i + 1];
            o0 = o0 > 0.f ? o0 : expm1f(o0);
            o1 = o1 > 0.f ? o1 : expm1f(o1);
            p[i] = __floats2half2_rn(o0, o1);
        }
        uint4 uo;
        uo.x = *(unsigned*)&p[0];
        uo.y = *(unsigned*)&p[1];
        uo.z = *(unsigned*)&p[2];
        uo.w = *(unsigned*)&p[3];
        *(uint4*)&ldsA[r][c] = uo;
    } else {
        uint4 z = {0u, 0u, 0u, 0u};
        *(uint4*)&ldsA[r][c] = z;
    }
    __syncthreads();
    // -------- phase 2: GEMM over the block's 16-row tile + attn epilogue ---
    int wave = tid >> 6, lane = tid & 63;
    int quad = lane >> 4, c15 = lane & 15;
    int row0 = blockIdx.x * 16;
    int t0 = (NT == 8) ? 2 * wave : 0;
    bool act = (NT == 8) || (wave == 0);
    if (act) {
        f32x4 a0c, a1c;
        a0c[0] = 0.f; a0c[1] = 0.f; a0c[2] = 0.f; a0c[3] = 0.f;
        a1c = a0c;
#pragma unroll
        for (int ks = 0; ks < NK; ++ks) {
            f16x8 a = *(f16x8*)&ldsA[c15][quad * 8 + ks * 32];
            f16x8 b0 = *(const f16x8*)(Whf +
                        (size_t)((t0 * NK + ks) * 64 + lane) * 8);
            f16x8 b1 = *(const f16x8*)(Whf +
                        (size_t)(((t0 + 1) * NK + ks) * 64 + lane) * 8);
            a0c = __builtin_amdgcn_mfma_f32_16x16x32_f16(a, b0, a0c, 0, 0, 0);
            a1c = __builtin_amdgcn_mfma_f32_16x16x32_f16(a, b1, a1c, 0, 0, 0);
        }
        // store Y (row = quad*4+rr, col = t*16+c15)
#pragma unroll
        for (int rr = 0; rr < 4; ++rr) {
            int row = row0 + quad * 4 + rr;
            if (row < N) {
                Y[(size_t)row * NOUT + t0 * 16 + c15] = (__half)a0c[rr];
                Y[(size_t)row * NOUT + (t0 + 1) * 16 + c15] = (__half)a1c[rr];
            }
        }
        // attention epilogue for head hd = t0/2
        int hd = t0 >> 1;
        float as0 = a_src[t0 * 16 + c15], as1 = a_src[(t0 + 1) * 16 + c15];
        float ad0 = a_dst[t0 * 16 + c15], ad1 = a_dst[(t0 + 1) * 16 + c15];
#pragma unroll
        for (int rr = 0; rr < 4; ++rr) {
            float s = a0c[rr] * as0 + a1c[rr] * as1;
            float dd = a0c[rr] * ad0 + a1c[rr] * ad1;
#pragma unroll
            for (int off = 8; off >= 1; off >>= 1) {
                s += __shfl_xor(s, off);
                dd += __shfl_xor(dd, off);
            }
            int row = row0 + quad * 4 + rr;
            if (row < N) {
                if (c15 == 0) es_o[row * HH + hd] = s;
                if (c15 == 1) ed_o[row * HH + hd] = dd;
            }
        }
    }
}

// ---------- layer 3: aggregate (D=32) + bias + LN + ELU + pool --------------
// 8 dsts per 64-lane wave: 8 lanes per dst (cl = lane&7), 4 channels each via
// uint2 (8 B) loads. 32 dsts per block.
__global__ __launch_bounds__(256) void aggr_ln32_pool_kernel(
    const int* __restrict__ rowptr, const int* __restrict__ csrc,
    const __half* __restrict__ h, const float* __restrict__ es,
    const float* __restrict__ ed, const float* __restrict__ bias,
    const float* __restrict__ gam, const float* __restrict__ bet,
    const int* __restrict__ batch, float* __restrict__ psum,
    unsigned* __restrict__ pmax, float* __restrict__ cnt, int N) {
    constexpr int D = 32;
    __shared__ float lsum[2][32];
    __shared__ unsigned lmax[2][32];
    __shared__ float lcnt[2];
    __shared__ int g0s;
    int tid = threadIdx.x;
    int d = (blockIdx.x * 256 + tid) >> 3;   // 8-lane group per dst
    int cl = tid & 7;
    int c = cl * 4;
    int dbase = blockIdx.x * 32;  // first node of this block
    if (tid < 64) {
        lsum[tid >> 5][tid & 31] = 0.f;
        lmax[tid >> 5][tid & 31] = 0u;
    }
    if (tid < 2) lcnt[tid] = 0.f;
    if (tid == 0) g0s = batch[dbase < N ? dbase : (N - 1)];
    __syncthreads();
    int g0 = g0s;
    if (d < N) {
        float edv = ed[d];
        float acc[4] = {0.f, 0.f, 0.f, 0.f};
        float l = 0.f;
        int k = rowptr[d], end = rowptr[d + 1];
        for (; k + 8 <= end; k += 8) {
            int s[8];
#pragma unroll
            for (int j = 0; j < 8; ++j) s[j] = csrc[k + j];
            float e[8];
#pragma unroll
            for (int j = 0; j < 8; ++j) e[j] = es[s[j]];
            uint2 u[8];
#pragma unroll
            for (int j = 0; j < 8; ++j)
                u[j] = *(const uint2*)(h + (size_t)s[j] * D + c);
#pragma unroll
            for (int j = 0; j < 8; ++j) {
                float w = __expf(lrelu(e[j] + edv));
                l += w;
                float2 f0 = __half22float2(*(__half2*)&u[j].x);
                float2 f1 = __half22float2(*(__half2*)&u[j].y);
                acc[0] += w * f0.x; acc[1] += w * f0.y;
                acc[2] += w * f1.x; acc[3] += w * f1.y;
            }
        }
        for (; k + 4 <= end; k += 4) {
            int s[4];
#pragma unroll
            for (int j = 0; j < 4; ++j) s[j] = csrc[k + j];
            float e[4];
#pragma unroll
            for (int j = 0; j < 4; ++j) e[j] = es[s[j]];
            uint2 u[4];
#pragma unroll
            for (int j = 0; j < 4; ++j)
                u[j] = *(const uint2*)(h + (size_t)s[j] * D + c);
#pragma unroll
            for (int j = 0; j < 4; ++j) {
                float w = __expf(lrelu(e[j] + edv));
                l += w;
                float2 f0 = __half22float2(*(__half2*)&u[j].x);
                float2 f1 = __half22float2(*(__half2*)&u[j].y);
                acc[0] += w * f0.x; acc[1] += w * f0.y;
                acc[2] += w * f1.x; acc[3] += w * f1.y;
            }
        }
        for (; k < end; ++k) {
            int s = csrc[k];
            float w = __expf(lrelu(es[s] + edv));
            uint2 u = *(const uint2*)(h + (size_t)s * D + c);
            l += w;
            float2 f0 = __half22float2(*(__half2*)&u.x);
            float2 f1 = __half22float2(*(__half2*)&u.y);
            acc[0] += w * f0.x; acc[1] += w * f0.y;
            acc[2] += w * f1.x; acc[3] += w * f1.y;
        }
        float rl = 1.f / (l + 1e-16f);
        float4 b4 = *(const float4*)(bias + c);
        float v0 = acc[0] * rl + b4.x;
        float v1 = acc[1] * rl + b4.y;
        float v2 = acc[2] * rl + b4.z;
        float v3 = acc[3] * rl + b4.w;
        float sm = v0 + v1 + v2 + v3;
        float ssum = v0 * v0 + v1 * v1 + v2 * v2 + v3 * v3;
#pragma unroll
        for (int off = 1; off <= 4; off <<= 1) {
            sm += __shfl_xor(sm, off);
            ssum += __shfl_xor(ssum, off);
        }
        float mean = sm / D;
        float var = ssum / D - mean * mean;
        float rstd = rsqrtf(var + 1e-5f);
        float4 g4 = *(const float4*)(gam + c);
        float4 t4 = *(const float4*)(bet + c);
        float o0 = (v0 - mean) * rstd * g4.x + t4.x;
        float o1 = (v1 - mean) * rstd * g4.y + t4.y;
        float o2 = (v2 - mean) * rstd * g4.z + t4.z;
        float o3 = (v3 - mean) * rstd * g4.w + t4.w;
        o0 = o0 > 0.f ? o0 : expm1f(o0);
        o1 = o1 > 0.f ? o1 : expm1f(o1);
        o2 = o2 > 0.f ? o2 : expm1f(o2);
        o3 = o3 > 0.f ? o3 : expm1f(o3);
        int g = batch[d];
        int goff = g - g0;
        if (goff >= 0 && goff < 2) {
            atomicAdd(&lsum[goff][c + 0], o0);
            atomicAdd(&lsum[goff][c + 1], o1);
            atomicAdd(&lsum[goff][c + 2], o2);
            atomicAdd(&lsum[goff][c + 3], o3);
            atomicMax(&lmax[goff][c + 0], encf(o0));
            atomicMax(&lmax[goff][c + 1], encf(o1));
            atomicMax(&lmax[goff][c + 2], encf(o2));
            atomicMax(&lmax[goff][c + 3], encf(o3));
            if (cl == 0) atomicAdd(&lcnt[goff], 1.0f);
        } else {
            atomicAdd(&psum[g * D + c + 0], o0);
            atomicAdd(&psum[g * D + c + 1], o1);
            atomicAdd(&psum[g * D + c + 2], o2);
            atomicAdd(&psum[g * D + c + 3], o3);
            atomicMax(&pmax[g * D + c + 0], encf(o0));
            atomicMax(&pmax[g * D + c + 1], encf(o1));
            atomicMax(&pmax[g * D + c + 2], encf(o2));
            atomicMax(&pmax[g * D + c + 3], encf(o3));
            if (cl == 0) atomicAdd(&cnt[g], 1.0f);
        }
    }
    __syncthreads();
    if (tid < 64) {
        int go = tid >> 5, cc = tid & 31;
        unsigned m = lmax[go][cc];
        if (m != 0u) {
            int gg = g0 + go;
            atomicAdd(&psum[gg * D + cc], lsum[go][cc]);
            atomicMax(&pmax[gg * D + cc], m);
            if (cc == 0) atomicAdd(&cnt[gg], lcnt[go]);
        }
    }
}

// ---------- fallback aggregation (online softmax, generic shapes) -----------
__global__ __launch_bounds__(256) void aggr_csr_kernel(
    const int* __restrict__ rowptr, const int* __restrict__ csrc,
    const float* __restrict__ h, const float* __restrict__ es,
    const float* __restrict__ ed, float* __restrict__ outp, int N, int H,
    int C) {
    int D = H * C;
    int wave = (blockIdx.x * blockDim.x + threadIdx.x) >> 6;
    int lane = threadIdx.x & 63;
    if (wave >= N) return;
    int d = wave;
    int c0 = lane, c1 = lane + 64;
    bool a0 = c0 < D, a1 = c1 < D;
    int h0 = a0 ? c0 / C : 0;
    int h1 = a1 ? c1 / C : 0;
    float edv0 = a0 ? ed[d * H + h0] : 0.f;
    float edv1 = a1 ? ed[d * H + h1] : 0.f;
    float m0 = -INFINITY, m1 = -INFINITY;
    float l0 = 0.f, l1 = 0.f, acc0 = 0.f, acc1 = 0.f;
    int beg = rowptr[d], end = rowptr[d + 1];
    for (int k = beg; k < end; ++k) {
        int s = csrc[k];
        const float* hp = h + (size_t)s * D;
        if (a0) {
            float v = lrelu(es[s * H + h0] + edv0);
            float nm = fmaxf(m0, v);
            float sc = __expf(m0 - nm);
            float w = __expf(v - nm);
            l0 = l0 * sc + w;
            acc0 = acc0 * sc + w * hp[c0];
            m0 = nm;
        }
        if (a1) {
            float v = lrelu(es[s * H + h1] + edv1);
            float nm = fmaxf(m1, v);
            float sc = __expf(m1 - nm);
            float w = __expf(v - nm);
            l1 = l1 * sc + w;
            acc1 = acc1 * sc + w * hp[c1];
            m1 = nm;
        }
    }
    if (a0) outp[(size_t)d * D + c0] = acc0 / (l0 + 1e-16f);
    if (a1) outp[(size_t)d * D + c1] = acc1 / (l1 + 1e-16f);
}

// ---------- bias + LayerNorm + ELU (fallback path) --------------------------
__global__ __launch_bounds__(64) void ln_elu_kernel(
    const float* __restrict__ in, const float* __restrict__ bias,
    const float* __restrict__ gam, const float* __restrict__ bet,
    float* __restrict__ outp, int D) {
    int n = blockIdx.x;
    int lane = threadIdx.x;  // blockDim = 64
    int c0 = lane, c1 = lane + 64;
    bool a0 = c0 < D, a1 = c1 < D;
    float v0 = 0.f, v1 = 0.f;
    if (a0) v0 = in[(size_t)n * D + c0] + bias[c0];
    if (a1) v1 = in[(size_t)n * D + c1] + bias[c1];
    float s = v0 + v1;
    float ss = v0 * v0 + v1 * v1;
    for (int off = 32; off; off >>= 1) {
        s += __shfl_xor(s, off);
        ss += __shfl_xor(ss, off);
    }
    float mean = s / D;
    float var = ss / D - mean * mean;
    float rstd = rsqrtf(var + 1e-5f);
    if (a0) {
        float o = (v0 - mean) * rstd * gam[c0] + bet[c0];
        outp[(size_t)n * D + c0] = o > 0.f ? o : expm1f(o);
    }
    if (a1) {
        float o = (v1 - mean) * rstd * gam[c1] + bet[c1];
        outp[(size_t)n * D + c1] = o > 0.f ? o : expm1f(o);
    }
}

// ---------- graph pooling (fallback path) -----------------------------------
__global__ __launch_bounds__(256) void pool_kernel(
    const float* __restrict__ h, const int* __restrict__ batch, int N, int C,
    float* __restrict__ psum, unsigned* __restrict__ pmax,
    float* __restrict__ cnt) {
    int idx = blockIdx.x * blockDim.x + threadIdx.x;
    if (idx >= N * C) return;
    int n = idx / C;
    int c = idx - n * C;
    int g = batch[n];
    float v = h[(size_t)n * C + c];
    atomicAdd(&psum[g * C + c], v);
    atomicMax(&pmax[g * C + c], encf(v));
    if (c == 0) atomicAdd(&cnt[g], 1.0f);
}

// ---------- classifier MLP: one block (1 wave) per graph --------------------
__global__ __launch_bounds__(64) void mlp_kernel(
    const float* __restrict__ psum, const unsigned* __restrict__ pmax,
    const float* __restrict__ cnt, const float* __restrict__ cW1,
    const float* __restrict__ cb1, const float* __restrict__ cW2,
    const float* __restrict__ cb2, const float* __restrict__ cW3,
    const float* __restrict__ cb3, float* __restrict__ outp, int C) {
    __shared__ float f[64];
    __shared__ float t1[32];
    __shared__ float t2[16];
    int g = blockIdx.x;
    int t = threadIdx.x;
    float c = fmaxf(cnt[g], 1.0f);
    if (t < C) {
        f[t] = psum[g * C + t] / c;
    } else if (t < 2 * C) {
        unsigned k = pmax[g * C + (t - C)];
        f[t] = (k == 0u) ? -INFINITY : decf(k);
    }
    __syncthreads();
    if (t < 32) {
        float a = cb1[t];
        for (int i = 0; i < 64; ++i) a += f[i] * cW1[t * 64 + i];
        t1[t] = fmaxf(a, 0.f);
    }
    __syncthreads();
    if (t < 16) {
        float a = cb2[t];
        for (int i = 0; i < 32; ++i) a += t1[i] * cW2[t * 32 + i];
        t2[t] = fmaxf(a, 0.f);
    }
    __syncthreads();
    if (t == 0) {
        float a = cb3[0];
        for (int i = 0; i < 16; ++i) a += t2[i] * cW3[i];
        outp[g] = a;
    }
}

// ---------------------------------------------------------------------------
extern "C" void kernel_launch(void* const* d_in, const int* in_sizes, int n_in,
                              void* d_out, int out_size, void* d_ws,
                              size_t ws_size, hipStream_t stream) {
    const float* x = (const float*)d_in[0];
    const int* ei = (const int*)d_in[1];
    const int* batch = (const int*)d_in[2];
    const float* W1 = (const float*)d_in[4];
    const float* as1 = (const float*)d_in[5];
    const float* ad1 = (const float*)d_in[6];
    const float* b1 = (const float*)d_in[7];
    const float* g1 = (const float*)d_in[8];
    const float* be1 = (const float*)d_in[9];
    const float* W2 = (const float*)d_in[10];
    const float* as2 = (const float*)d_in[11];
    const float* ad2 = (const float*)d_in[12];
    const float* b2 = (const float*)d_in[13];
    const float* g2 = (const float*)d_in[14];
    const float* be2 = (const float*)d_in[15];
    const float* W3 = (const float*)d_in[16];
    const float* as3 = (const float*)d_in[17];
    const float* ad3 = (const float*)d_in[18];
    const float* b3 = (const float*)d_in[19];
    const float* g3 = (const float*)d_in[20];
    const float* be3 = (const float*)d_in[21];
    const float* cW1 = (const float*)d_in[22];
    const float* cb1 = (const float*)d_in[23];
    const float* cW2 = (const float*)d_in[24];
    const float* cb2 = (const float*)d_in[25];
    const float* cW3 = (const float*)d_in[26];
    const float* cb3 = (const float*)d_in[27];

    const int N = in_sizes[2];            // 50000
    const int E = in_sizes[1] / 2;        // 800000
    const int F0 = in_sizes[0] / N;       // 32
    const int Hd = in_sizes[19];          // 32 (b3)
    const int H = in_sizes[5] / Hd;       // 4
    const int D = H * Hd;                 // 128
    const int H3 = in_sizes[17] / Hd;     // 1
    const int G = out_size;               // 512
    const int EN = E + N;
    const bool shapes_ok = (F0 == 32 && Hd == 32 && H == 4 && D == 128 &&
                            H3 == 1 && N <= 65536);

    // -------- workspace carve-out (256B aligned) --------
    char* w = (char*)d_ws;
    size_t off = 0;
    auto carve = [&](size_t bytes) -> void* {
        void* p = w + off;
        off = (off + bytes + 255) & ~(size_t)255;
        return p;
    };
    float* Q = (float*)carve((size_t)N * D * 4);      // fallback fp32 staging
    __half* Qh = (__half*)Q;                          // main path fp16 h1/h3
    float* R = (float*)carve((size_t)N * D * 4);      // fallback scratch
    float* P = (float*)carve((size_t)N * D * 4);      // fallback activations
    __half* Ph = (__half*)P;                          // main path fp16 h2
    float* es1 = (float*)carve((size_t)N * H * 4);
    float* ed1 = (float*)carve((size_t)N * H * 4);
    float* es2 = (float*)carve((size_t)N * H * 4);
    float* ed2 = (float*)carve((size_t)N * H * 4);
    int* rowptr = (int*)carve((size_t)(N + 1) * 4);
    int* cursor = (int*)carve((size_t)N * 4);
    int* csrc = (int*)carve((size_t)EN * 4);
    int* bsum = (int*)carve((size_t)CDIV(N, SCAN_BS) * 4);
    const int nblkA = CDIV(E, ATILE);
    int* ghist = (int*)carve((size_t)nblkA * NBUK * 4);
    int* tot = (int*)carve((size_t)NBUK * 4);
    unsigned* ebuf = (unsigned*)carve((size_t)E * 4);
    __half* wh2 = (__half*)carve((size_t)8 * 4 * 64 * 8 * 2);
    __half* wh3 = (__half*)carve((size_t)2 * 4 * 64 * 8 * 2);
    // psum/pmax/cnt carved contiguously (sizes are 256B multiples) so one
    // zero-fill covers all three.
    float* psum = (float*)carve((size_t)G * Hd * 4);
    unsigned* pmax = (unsigned*)carve((size_t)G * Hd * 4);
    float* cnt = (float*)carve((size_t)G * 4);
    (void)ws_size;
    (void)n_in;

    const int BLK = 256;
    const int nb = CDIV(N, SCAN_BS);
    const int poolInts = G * Hd * 2 + G;  // psum + pmax + cnt (ints)

    if (shapes_ok) {
        // ---- bucketed CSR build; binA1 also zero-fills pooling buffers,
        //      runs wh2/wh3 swizzles (10 blocks) AND the full layer-1
        //      GEMM+attn (inline W1->LDS swizzle) as extra block ranges ----
        const int nwp = 10;                  // 2560 threads for wh2+wh3
        const int ngemm1 = CDIV(N, 64);
        binA1_kernel<<<nblkA + nwp + ngemm1, 256, 0, stream>>>(
            ei, E, ghist, (int*)psum, poolInts, W1, W2, W3, wh2, wh3,
            rowptr, N, nblkA, nwp, x, Qh, as1, ad1, es1, ed1);
        binA2a_kernel<<<NBUK, 64, 0, stream>>>(ghist, tot, nblkA);
        binA3_kernel<<<nblkA, 256, 0, stream>>>(ei, E, ghist, tot, ebuf);
        binB_kernel<<<CDIV(N, 128), 256, 0, stream>>>(ebuf, tot, rowptr,
                                                      csrc, N);
        // fused: layer-1 aggregation + LN + ELU -> LDS -> layer-2 GEMM+attn
        // reads h1=Qh,es1/ed1; writes h2=Ph,es2/ed2 (disjoint buffers)
        aggr_gemm_kernel<128, 4><<<CDIV(N, 16), 256, 0, stream>>>(
            rowptr, csrc, Qh, es1, ed1, b1, g1, be1, wh2, Ph, as2, ad2,
            es2, ed2, N);
        // fused: layer-2 aggregation + LN + ELU -> LDS -> layer-3 GEMM+attn
        // reads h2=Ph,es2/ed2; writes h3=Qh (N x 32 fp16), es1/ed1 (N x 1)
        aggr_gemm_kernel<32, 1><<<CDIV(N, 16), 256, 0, stream>>>(
            rowptr, csrc, Ph, es2, ed2, b2, g2, be2, wh3, Qh, as3, ad3,
            es1, ed1, N);
        // layer 3 aggregation (+ fused pooling)
        aggr_ln32_pool_kernel<<<CDIV(N, 32), 256, 0, stream>>>(
            rowptr, csrc, Qh, es1, ed1, b3, g3, be3, batch, psum, pmax,
            cnt, N);
    } else {
        // generic fallback path (all fp32, plain CSR build)
        float* es = es1;
        float* ed = ed1;
        hipMemsetAsync(psum, 0, (size_t)G * Hd * 4, stream);
        hipMemsetAsync(pmax, 0, (size_t)G * Hd * 4, stream);
        hipMemsetAsync(cnt, 0, (size_t)G * 4, stream);
        hipMemsetAsync(cursor, 0, (size_t)N * 4, stream);
        deg_kernel<<<CDIV(E, BLK), BLK, 0, stream>>>(ei, E, cursor);
        scan1_kernel<<<nb, SCAN_BS, 0, stream>>>(cursor, rowptr, bsum, N);
        scan2_kernel<<<1, 64, 0, stream>>>(bsum, nb);
        scan3_kernel<<<nb, SCAN_BS, 0, stream>>>(rowptr, cursor, csrc, bsum, N, EN);
        scatter_kernel<<<CDIV(E, BLK), BLK, 0, stream>>>(ei, E, cursor, csrc);
        gemm_kernel<<<CDIV(N * D, BLK), BLK, 0, stream>>>(x, W1, Q, N, F0, D);
        attn_kernel<<<CDIV(N * H, BLK), BLK, 0, stream>>>(Q, as1, ad1, es, ed, N, H, Hd);
        aggr_csr_kernel<<<CDIV(N, 4), BLK, 0, stream>>>(rowptr, csrc, Q, es, ed, R, N, H, Hd);
        ln_elu_kernel<<<N, 64, 0, stream>>>(R, b1, g1, be1, P, D);
        gemm_kernel<<<CDIV(N * D, BLK), BLK, 0, stream>>>(P, W2, Q, N, D, D);
        attn_kernel<<<CDIV(N * H, BLK), BLK, 0, stream>>>(Q, as2, ad2, es, ed, N, H, Hd);
        aggr_csr_kernel<<<CDIV(N, 4), BLK, 0, stream>>>(rowptr, csrc, Q, es, ed, R, N, H, Hd);
        ln_elu_kernel<<<N, 64, 0, stream>>>(R, b2, g2, be2, P, D);
        gemm_kernel<<<CDIV(N * Hd, BLK), BLK, 0, stream>>>(P, W3, Q, N, D, Hd);
        attn_kernel<<<CDIV(N * H3, BLK), BLK, 0, stream>>>(Q, as3, ad3, es, ed, N, H3, Hd);
        aggr_csr_kernel<<<CDIV(N, 4), BLK, 0, stream>>>(rowptr, csrc, Q, es, ed, R, N, H3, Hd);
        ln_elu_kernel<<<N, 64, 0, stream>>>(R, b3, g3, be3, P, Hd);
        pool_kernel<<<CDIV(N * Hd, BLK), BLK, 0, stream>>>(P, batch, N, Hd, psum, pmax, cnt);
    }

    mlp_kernel<<<G, 64, 0, stream>>>(psum, pmax, cnt, cW1, cb1, cW2, cb2, cW3,
                                     cb3, (float*)d_out, Hd);
}

// Round 9
// 263.013 us; speedup vs baseline: 1.5101x; 1.5101x over previous
//
#include <hip/hip_runtime.h>
#include <hip/hip_fp16.h>
#include <math.h>

#define CDIV(a, b) (((a) + (b) - 1) / (b))
#define SCAN_BS 1024
#define NBUK 512          // dst buckets (dst>>7); covers N <= 65536
#define ATILE 4096        // edges per Stage-A block

typedef _Float16 f16x8 __attribute__((ext_vector_type(8)));
typedef float f32x4 __attribute__((ext_vector_type(4)));

// ---------- float <-> monotone-unsigned encoding for atomicMax on floats ----
__device__ __forceinline__ unsigned encf(float v) {
    unsigned u = __float_as_uint(v);
    return (u & 0x80000000u) ? ~u : (u | 0x80000000u);
}
__device__ __forceinline__ float decf(unsigned k) {
    unsigned u = (k & 0x80000000u) ? (k ^ 0x80000000u) : ~k;
    return __uint_as_float(u);
}

__device__ __forceinline__ float lrelu(float v) {
    return v > 0.f ? v : 0.2f * v;
}

// ---------- naive GEMM fallback (only if shapes are unexpected) -------------
__global__ __launch_bounds__(256) void gemm_kernel(
    const float* __restrict__ X, const float* __restrict__ W,
    float* __restrict__ Y, int M, int K, int Nout) {
    int idx = blockIdx.x * blockDim.x + threadIdx.x;
    if (idx >= M * Nout) return;
    int row = idx / Nout;
    int col = idx - row * Nout;
    const float* xr = X + (size_t)row * K;
    const float* wc = W + col;
    float acc = 0.f;
    for (int k = 0; k < K; k += 4) {
        float4 xv = *(const float4*)(xr + k);
        acc += xv.x * wc[(size_t)(k + 0) * Nout];
        acc += xv.y * wc[(size_t)(k + 1) * Nout];
        acc += xv.z * wc[(size_t)(k + 2) * Nout];
        acc += xv.w * wc[(size_t)(k + 3) * Nout];
    }
    Y[idx] = acc;
}

// ---------- weight prep: swizzle W (K x NOUT fp32) into B-fragment order ----
__device__ __forceinline__ void wprep_one(const float* __restrict__ W,
                                          __half* __restrict__ Whf, int K,
                                          int NOUT, int idx) {
    int NK = K / 32;
    int l = idx & 63, f = idx >> 6;
    int ks = f % NK, tt = f / NK;
    int quad = l >> 4, c15 = l & 15;
    _Float16 v[8];
#pragma unroll
    for (int j = 0; j < 8; ++j) {
        int k = ks * 32 + quad * 8 + j;
        int n = tt * 16 + c15;
        v[j] = (_Float16)W[(size_t)k * NOUT + n];
    }
    *(uint4*)(Whf + (size_t)idx * 8) = *(uint4*)v;
}

// LDS-destination variant (same math; generic-pointer store works for LDS)
__device__ __forceinline__ void wprep_one_lds(const float* __restrict__ W,
                                              __half* Whf, int K, int NOUT,
                                              int idx) {
    int NK = K / 32;
    int l = idx & 63, f = idx >> 6;
    int ks = f % NK, tt = f / NK;
    int quad = l >> 4, c15 = l & 15;
    _Float16 v[8];
#pragma unroll
    for (int j = 0; j < 8; ++j) {
        int k = ks * 32 + quad * 8 + j;
        int n = tt * 16 + c15;
        v[j] = (_Float16)W[(size_t)k * NOUT + n];
    }
    *(uint4*)(Whf + (size_t)idx * 8) = *(uint4*)v;
}

// ---------- A-fragment loaders ----------------------------------------------
__device__ __forceinline__ f16x8 loadA(const float* p) {
    float4 lo = *(const float4*)p;
    float4 hi = *(const float4*)(p + 4);
    f16x8 a;
    a[0] = (_Float16)lo.x; a[1] = (_Float16)lo.y;
    a[2] = (_Float16)lo.z; a[3] = (_Float16)lo.w;
    a[4] = (_Float16)hi.x; a[5] = (_Float16)hi.y;
    a[6] = (_Float16)hi.z; a[7] = (_Float16)hi.w;
    return a;
}
__device__ __forceinline__ f16x8 loadA(const __half* p) {
    return *(const f16x8*)p;
}

// ---------- MFMA GEMM + fused attention-coefficient epilogue (body) ---------
// Y[M,NOUT] (fp16) = X[M,K] @ B-fragments bp; es/ed[M,HH] from the fp32
// accumulators (head h covers channels [32h,32h+32) = tiles 2h,2h+1).
template <int K, int NOUT, int HH, typename XT, typename BP>
__device__ __forceinline__ void gemm_attn_body(
    const XT* __restrict__ X, const BP* bp, __half* __restrict__ Y,
    const float* __restrict__ a_src, const float* __restrict__ a_dst,
    float* __restrict__ es, float* __restrict__ ed, int M, int blk) {
    constexpr int NK = K / 32, NT = NOUT / 16;
    static_assert(NT == 2 * HH, "32 channels per head assumed");
    int wave = threadIdx.x >> 6, lane = threadIdx.x & 63;
    int quad = lane >> 4, c15 = lane & 15;
    int row0 = (blk * 4 + wave) * 16;
    if (row0 >= M) return;  // uniform per wave
    int arow = row0 + c15;
    if (arow >= M) arow = M - 1;
    const XT* xr = X + (size_t)arow * K + quad * 8;
    f32x4 acc[NT];
#pragma unroll
    for (int t = 0; t < NT; ++t) {
        acc[t][0] = 0.f; acc[t][1] = 0.f; acc[t][2] = 0.f; acc[t][3] = 0.f;
    }
#pragma unroll
    for (int ks = 0; ks < NK; ++ks) {
        f16x8 a = loadA(xr + ks * 32);
#pragma unroll
        for (int t = 0; t < NT; ++t) {
            f16x8 b = *(const f16x8*)&bp[((t * NK + ks) * 64 + lane) * 8];
            acc[t] = __builtin_amdgcn_mfma_f32_16x16x32_f16(a, b, acc[t],
                                                            0, 0, 0);
        }
    }
    // store Y (C/D mapping: row = quad*4+r, col = t*16+c15)
#pragma unroll
    for (int r = 0; r < 4; ++r) {
        int row = row0 + quad * 4 + r;
        if (row < M) {
#pragma unroll
            for (int t = 0; t < NT; ++t)
                Y[(size_t)row * NOUT + t * 16 + c15] = (__half)acc[t][r];
        }
    }
    // attention epilogue: es[row,h] = sum_c Y[row,32h+c]*a_src[32h+c]
    float asv[NT], adv[NT];
#pragma unroll
    for (int t = 0; t < NT; ++t) {
        asv[t] = a_src[t * 16 + c15];
        adv[t] = a_dst[t * 16 + c15];
    }
#pragma unroll
    for (int h = 0; h < HH; ++h) {
#pragma unroll
        for (int r = 0; r < 4; ++r) {
            float s = acc[2 * h][r] * asv[2 * h] +
                      acc[2 * h + 1][r] * asv[2 * h + 1];
            float dd = acc[2 * h][r] * adv[2 * h] +
                       acc[2 * h + 1][r] * adv[2 * h + 1];
#pragma unroll
            for (int off = 8; off >= 1; off >>= 1) {
                s += __shfl_xor(s, off);     // stays inside the 16-lane quad
                dd += __shfl_xor(dd, off);
            }
            int row = row0 + quad * 4 + r;
            if (row < M) {
                if (c15 == 0) es[row * HH + h] = s;
                if (c15 == 1) ed[row * HH + h] = dd;
            }
        }
    }
}

// ============ Bucketed CSR build ============================================
// Stage A1: per-block bucket histogram (bucket = dst>>7). Side jobs folded in:
//   - zero-fills the pooling buffers (replaces 3 hipMemsetAsync dispatches)
//   - blocks [nhist, nhist+nwp): wh2/wh3 weight swizzles + rowptr[N] sentinel
//   - blocks >= nhist+nwp: layer-1 GEMM+attn with inline W1->LDS swizzle
//     (gemm1 has no CSR dependency; overlaps with the histogram phase)
__global__ __launch_bounds__(256) void binA1_kernel(
    const int* __restrict__ ei, int E, int* __restrict__ ghist,
    int* __restrict__ pool0, int poolN, const float* __restrict__ W1,
    const float* __restrict__ W2, const float* __restrict__ W3,
    __half* __restrict__ wh2, __half* __restrict__ wh3,
    int* __restrict__ rowptr, int N, int nhist, int nwp,
    const float* __restrict__ x, __half* __restrict__ Qh,
    const float* __restrict__ as1, const float* __restrict__ ad1,
    float* __restrict__ es, float* __restrict__ ed) {
    __shared__ int lh[NBUK];
    __shared__ __half wlds[512 * 8];   // 8 KB: W1 fragments for gemm1 blocks
    int t = threadIdx.x;
    if (blockIdx.x >= nhist + nwp) {   // ---- gemm1 blocks ----
        for (int i = t; i < 512; i += 256)
            wprep_one_lds(W1, wlds, 32, 128, i);
        __syncthreads();
        gemm_attn_body<32, 128, 4>(x, wlds, Qh, as1, ad1, es, ed, N,
                                   blockIdx.x - nhist - nwp);
        return;
    }
    if (blockIdx.x >= nhist) {         // ---- weight-prep blocks (wh2/wh3) --
        int idx = (blockIdx.x - nhist) * 256 + t;
        if (idx == 0) rowptr[N] = E + N;
        if (idx < 2048) {
            wprep_one(W2, wh2, 128, 128, idx);         // 8*4*64 = 2048
        } else if (idx < 2560) {
            wprep_one(W3, wh3, 128, 32, idx - 2048);   // 2*4*64 = 512
        }
        return;
    }
    int gid = blockIdx.x * 256 + t;
    if (gid < poolN) pool0[gid] = 0;
    for (int i = t; i < NBUK; i += 256) lh[i] = 0;
    __syncthreads();
    int base = blockIdx.x * ATILE;
#pragma unroll 4
    for (int j = 0; j < ATILE / 256; ++j) {
        int idx = base + t + 256 * j;
        if (idx < E) atomicAdd(&lh[ei[E + idx] >> 7], 1);
    }
    __syncthreads();
    int* gh = ghist + (size_t)blockIdx.x * NBUK;
    for (int i = t; i < NBUK; i += 256) gh[i] = lh[i];
}

// Stage A2: one wave per bucket — exclusive prefix over blocks (column scan)
__global__ __launch_bounds__(64) void binA2a_kernel(
    int* __restrict__ ghist, int* __restrict__ tot, int nblk) {
    int b = blockIdx.x;
    int lane = threadIdx.x;
    int accb = 0;
    for (int chunk = 0; chunk < nblk; chunk += 64) {
        int i = chunk + lane;
        int v = (i < nblk) ? ghist[(size_t)i * NBUK + b] : 0;
        int s = v;
        for (int off = 1; off < 64; off <<= 1) {
            int tv = __shfl_up(s, off);
            if (lane >= off) s += tv;
        }
        if (i < nblk) ghist[(size_t)i * NBUK + b] = s - v + accb;  // exclusive
        accb += __shfl(s, 63);
    }
    if (lane == 0) tot[b] = accb;
}

// in-block exclusive scan over tot[NBUK] (256 threads, 2 elems each).
// On return: excl = prefix of element 2t; a0/a1 = tot[2t], tot[2t+1].
__device__ __forceinline__ void bucketScan(const int* __restrict__ tot,
                                           int* __restrict__ sc, int t,
                                           int& a0, int& a1, int& excl) {
    a0 = tot[2 * t];
    a1 = tot[2 * t + 1];
    int pair = a0 + a1;
    sc[t] = pair;
    __syncthreads();
#pragma unroll
    for (int off = 1; off < 256; off <<= 1) {
        int v = (t >= off) ? sc[t - off] : 0;
        __syncthreads();
        sc[t] += v;
        __syncthreads();
    }
    excl = sc[t] - pair;
}

// Stage A3: binned scatter of packed (dst<<16)|src into bucket-contiguous ebuf
// (bucket base offsets recomputed in-block from tot — no binA2b dispatch).
__global__ __launch_bounds__(256) void binA3_kernel(
    const int* __restrict__ ei, int E, const int* __restrict__ ghist,
    const int* __restrict__ tot, unsigned* __restrict__ ebuf) {
    __shared__ int lcur[NBUK];
    __shared__ int sc[256];
    int t = threadIdx.x;
    int a0, a1, excl;
    bucketScan(tot, sc, t, a0, a1, excl);
    const int* gh = ghist + (size_t)blockIdx.x * NBUK;
    lcur[2 * t] = gh[2 * t] + excl;
    lcur[2 * t + 1] = gh[2 * t + 1] + excl + a0;
    __syncthreads();
    int base = blockIdx.x * ATILE;
#pragma unroll 4
    for (int j = 0; j < ATILE / 256; ++j) {
        int idx = base + t + 256 * j;
        if (idx < E) {
            int s = ei[idx];
            int d = ei[E + idx];
            int pos = atomicAdd(&lcur[d >> 7], 1);
            ebuf[pos] = ((unsigned)d << 16) | (unsigned)s;
        }
    }
}

// Stage B: one block per bucket — local degree histogram + prefix gives
// rowptr (contiguous write) and the final CSR scatter into this bucket's
// private csrc region. Bucket range recomputed in-block from tot.
__global__ __launch_bounds__(256) void binB_kernel(
    const unsigned* __restrict__ ebuf, const int* __restrict__ tot,
    int* __restrict__ rowptr, int* __restrict__ csrc, int N) {
    __shared__ int cnt_[128];
    __shared__ int pre[128];
    __shared__ int lcur[128];
    __shared__ int sc[256];
    __shared__ int begS;
    int b = blockIdx.x;
    int t = threadIdx.x;
    int n0 = b << 7;
    int totb = tot[b];
    if (t < 128) cnt_[t] = 0;
    int a0, a1, excl;
    bucketScan(tot, sc, t, a0, a1, excl);
    if (t == (b >> 1)) begS = (b & 1) ? (excl + a0) : excl;
    __syncthreads();
    int beg = begS, end = begS + totb;
    for (int i = beg + t; i < end; i += 256)
        atomicAdd(&cnt_[(ebuf[i] >> 16) - n0], 1);
    __syncthreads();
    // inclusive scan of (cnt+1 if node valid else 0) over 128 entries
    if (t < 128) pre[t] = (n0 + t < N) ? (cnt_[t] + 1) : 0;
    __syncthreads();
    for (int off = 1; off < 128; off <<= 1) {
        int v = 0;
        if (t < 128 && t >= off) v = pre[t - off];
        __syncthreads();
        if (t < 128) pre[t] += v;
        __syncthreads();
    }
    int cbase = beg + n0;  // edges before bucket + self-loop slots before it
    if (t < 128 && n0 + t < N) {
        int ex = pre[t] - (cnt_[t] + 1);
        int rp = cbase + ex;
        rowptr[n0 + t] = rp;
        csrc[rp] = n0 + t;   // self-loop in slot 0
        lcur[t] = rp + 1;
    }
    __syncthreads();
    for (int i = beg + t; i < end; i += 256) {
        unsigned e = ebuf[i];
        int d = (int)(e >> 16) - n0;
        int s = (int)(e & 0xFFFFu);
        int pos = atomicAdd(&lcur[d], 1);
        csrc[pos] = s;
    }
}

// ---------- attention coefficients (fallback path, fp32) --------------------
__global__ __launch_bounds__(256) void attn_kernel(
    const float* __restrict__ h, const float* __restrict__ a_src,
    const float* __restrict__ a_dst, float* __restrict__ es,
    float* __restrict__ ed, int N, int H, int C) {
    int idx = blockIdx.x * blockDim.x + threadIdx.x;
    if (idx >= N * H) return;
    int n = idx / H;
    int hh = idx - n * H;
    const float* hp = h + (size_t)n * H * C + (size_t)hh * C;
    const float* ap = a_src + hh * C;
    const float* bp = a_dst + hh * C;
    float s = 0.f, d = 0.f;
    for (int c = 0; c < C; c += 4) {
        float4 hv = *(const float4*)(hp + c);
        float4 av = *(const float4*)(ap + c);
        float4 bv = *(const float4*)(bp + c);
        s += hv.x * av.x + hv.y * av.y + hv.z * av.z + hv.w * av.w;
        d += hv.x * bv.x + hv.y * bv.y + hv.z * bv.z + hv.w * bv.w;
    }
    es[idx] = s;
    ed[idx] = d;
}

// ---------- fallback CSR build (generic shapes) -----------------------------
__global__ __launch_bounds__(256) void deg_kernel(const int* __restrict__ ei,
                                                  int E,
                                                  int* __restrict__ deg) {
    int e = blockIdx.x * blockDim.x + threadIdx.x;
    if (e >= E) return;
    atomicAdd(&deg[ei[E + e]], 1);
}

__global__ __launch_bounds__(SCAN_BS) void scan1_kernel(
    const int* __restrict__ deg, int* __restrict__ rowptr,
    int* __restrict__ bsum, int N) {
    __shared__ int tmp[SCAN_BS];
    int tid = threadIdx.x;
    int gid = blockIdx.x * SCAN_BS + tid;
    int v = (gid < N) ? (deg[gid] + 1) : 0;
    tmp[tid] = v;
    __syncthreads();
    for (int off = 1; off < SCAN_BS; off <<= 1) {
        int t = (tid >= off) ? tmp[tid - off] : 0;
        __syncthreads();
        tmp[tid] += t;
        __syncthreads();
    }
    if (gid < N) rowptr[gid] = tmp[tid] - v;
    if (tid == SCAN_BS - 1) bsum[blockIdx.x] = tmp[tid];
}

__global__ void scan2_kernel(int* __restrict__ bsum, int nb) {
    if (threadIdx.x == 0 && blockIdx.x == 0) {
        int acc = 0;
        for (int i = 0; i < nb; ++i) {
            int t = bsum[i];
            bsum[i] = acc;
            acc += t;
        }
    }
}

__global__ __launch_bounds__(SCAN_BS) void scan3_kernel(
    int* __restrict__ rowptr, int* __restrict__ cursor,
    int* __restrict__ csrc, const int* __restrict__ bsum, int N, int total) {
    int gid = blockIdx.x * SCAN_BS + threadIdx.x;
    if (gid < N) {
        int v = rowptr[gid] + bsum[blockIdx.x];
        rowptr[gid] = v;
        cursor[gid] = v + 1;
        csrc[v] = gid;
    }
    if (gid == 0) rowptr[N] = total;
}

__global__ __launch_bounds__(256) void scatter_kernel(
    const int* __restrict__ ei, int E, int* __restrict__ cursor,
    int* __restrict__ csrc) {
    int e = blockIdx.x * blockDim.x + threadIdx.x;
    if (e >= E) return;
    int s = ei[e];
    int d = ei[E + e];
    int pos = atomicAdd(&cursor[d], 1);
    csrc[pos] = s;
}

// ====== FUSED: softmax-aggregate + bias + LN + ELU -> LDS -> next GEMM ======
// Phase 1 (identical math to the verified aggr_ln128): 16 dsts per block,
// 16 lanes per dst, uint4 gathers; LN+ELU result staged to LDS (fp16).
// Phase 2: the block's 16 rows are exactly one MFMA A-tile; 4 waves run
// Y[16,NOUT] = lds @ Whf + attention epilogue (wave w owns tiles 2w,2w+1 =
// head w for NOUT=128; wave 0 owns both tiles for NOUT=32).
template <int NOUT, int HH>
__global__ __launch_bounds__(256) void aggr_gemm_kernel(
    const int* __restrict__ rowptr, const int* __restrict__ csrc,
    const __half* __restrict__ h, const float* __restrict__ es,
    const float* __restrict__ ed, const float* __restrict__ bias,
    const float* __restrict__ gam, const float* __restrict__ bet,
    const __half* __restrict__ Whf, __half* __restrict__ Y,
    const float* __restrict__ a_src, const float* __restrict__ a_dst,
    float* __restrict__ es_o, float* __restrict__ ed_o, int N) {
    constexpr int D = 128, H = 4;          // aggregation-side geometry
    constexpr int NK = 4, NT = NOUT / 16;  // GEMM K = 128
    static_assert(NT == 2 * HH, "32 channels per head assumed");
    __shared__ __half lds[16][136];        // 16 rows, 128 + 8 pad (fp16)
    int tid = threadIdx.x;
    int r = tid >> 4;                      // block-local row 0..15
    int cl = tid & 15;
    int d = blockIdx.x * 16 + r;
    int c = cl * 8;
    // -------- phase 1: aggregation + bias + LN + ELU -> LDS --------
    if (d < N) {
        int hh = cl >> 2;                  // head = c/32
        float edv = ed[d * H + hh];
        float acc[8];
#pragma unroll
        for (int i = 0; i < 8; ++i) acc[i] = 0.f;
        float l = 0.f;
        int k = rowptr[d], end = rowptr[d + 1];
        for (; k + 8 <= end; k += 8) {
            int s[8];
#pragma unroll
            for (int j = 0; j < 8; ++j) s[j] = csrc[k + j];
            float e[8];
#pragma unroll
            for (int j = 0; j < 8; ++j) e[j] = es[s[j] * H + hh];
            uint4 u[8];
#pragma unroll
            for (int j = 0; j < 8; ++j)
                u[j] = *(const uint4*)(h + (size_t)s[j] * D + c);
#pragma unroll
            for (int j = 0; j < 8; ++j) {
                float w = __expf(lrelu(e[j] + edv));
                l += w;
                const __half2* hp = (const __half2*)&u[j];
#pragma unroll
                for (int i = 0; i < 4; ++i) {
                    float2 f = __half22float2(hp[i]);
                    acc[2 * i] += w * f.x;
                    acc[2 * i + 1] += w * f.y;
                }
            }
        }
        for (; k + 4 <= end; k += 4) {
            int s[4];
#pragma unroll
            for (int j = 0; j < 4; ++j) s[j] = csrc[k + j];
            float e[4];
#pragma unroll
            for (int j = 0; j < 4; ++j) e[j] = es[s[j] * H + hh];
            uint4 u[4];
#pragma unroll
            for (int j = 0; j < 4; ++j)
                u[j] = *(const uint4*)(h + (size_t)s[j] * D + c);
#pragma unroll
            for (int j = 0; j < 4; ++j) {
                float w = __expf(lrelu(e[j] + edv));
                l += w;
                const __half2* hp = (const __half2*)&u[j];
#pragma unroll
                for (int i = 0; i < 4; ++i) {
                    float2 f = __half22float2(hp[i]);
                    acc[2 * i] += w * f.x;
                    acc[2 * i + 1] += w * f.y;
                }
            }
        }
        for (; k < end; ++k) {
            int s = csrc[k];
            float w = __expf(lrelu(es[s * H + hh] + edv));
            uint4 u = *(const uint4*)(h + (size_t)s * D + c);
            l += w;
            const __half2* hp = (const __half2*)&u;
#pragma unroll
            for (int i = 0; i < 4; ++i) {
                float2 f = __half22float2(hp[i]);
                acc[2 * i] += w * f.x;
                acc[2 * i + 1] += w * f.y;
            }
        }
        float rl = 1.f / (l + 1e-16f);
        float4 b0 = *(const float4*)(bias + c);
        float4 b1 = *(const float4*)(bias + c + 4);
        float v[8];
        v[0] = acc[0] * rl + b0.x; v[1] = acc[1] * rl + b0.y;
        v[2] = acc[2] * rl + b0.z; v[3] = acc[3] * rl + b0.w;
        v[4] = acc[4] * rl + b1.x; v[5] = acc[5] * rl + b1.y;
        v[6] = acc[6] * rl + b1.z; v[7] = acc[7] * rl + b1.w;
        float sm = 0.f, ssum = 0.f;
#pragma unroll
        for (int i = 0; i < 8; ++i) { sm += v[i]; ssum += v[i] * v[i]; }
#pragma unroll
        for (int off = 1; off <= 8; off <<= 1) {   // 16-lane group reduce
            sm += __shfl_xor(sm, off);
            ssum += __shfl_xor(ssum, off);
        }
        float mean = sm / D;
        float var = ssum / D - mean * mean;
        float rstd = rsqrtf(var + 1e-5f);
        float4 g0 = *(const float4*)(gam + c);
        float4 g1 = *(const float4*)(gam + c + 4);
        float4 t0 = *(const float4*)(bet + c);
        float4 t1 = *(const float4*)(bet + c + 4);
        float gv[8] = {g0.x, g0.y, g0.z, g0.w, g1.x, g1.y, g1.z, g1.w};
        float tv[8] = {t0.x, t0.y, t0.z, t0.w, t1.x, t1.y, t1.z, t1.w};
        __half2 p[4];
#pragma unroll
        for (int i = 0; i < 4; ++i) {
            float o0 = (v[2 * i] - mean) * rstd * gv[2 * i] + tv[2 * i];
            float o1 = (v[2 * i + 1] - mean) * rstd * gv[2 * i + 1] +
                       tv[2 * i + 1];
            o0 = o0 > 0.f ? o0 : expm1f(o0);
            o1 = o1 > 0.f ? o1 : expm1f(o1);
            p[i] = __floats2half2_rn(o0, o1);
        }
        uint4 uo;
        uo.x = *(unsigned*)&p[0];
        uo.y = *(unsigned*)&p[1];
        uo.z = *(unsigned*)&p[2];
        uo.w = *(unsigned*)&p[3];
        *(uint4*)&lds[r][c] = uo;
    } else {
        uint4 z = {0u, 0u, 0u, 0u};
        *(uint4*)&lds[r][c] = z;
    }
    __syncthreads();
    // -------- phase 2: GEMM over the block's 16-row tile + attn epilogue ---
    int wave = tid >> 6, lane = tid & 63;
    int quad = lane >> 4, c15 = lane & 15;
    int row0 = blockIdx.x * 16;
    int t0 = (NT == 8) ? 2 * wave : 0;
    bool act = (NT == 8) || (wave == 0);
    if (act) {
        f32x4 a0c, a1c;
        a0c[0] = 0.f; a0c[1] = 0.f; a0c[2] = 0.f; a0c[3] = 0.f;
        a1c = a0c;
#pragma unroll
        for (int ks = 0; ks < NK; ++ks) {
            f16x8 a = *(f16x8*)&lds[c15][quad * 8 + ks * 32];
            f16x8 b0 = *(const f16x8*)(Whf +
                        (size_t)((t0 * NK + ks) * 64 + lane) * 8);
            f16x8 b1 = *(const f16x8*)(Whf +
                        (size_t)(((t0 + 1) * NK + ks) * 64 + lane) * 8);
            a0c = __builtin_amdgcn_mfma_f32_16x16x32_f16(a, b0, a0c, 0, 0, 0);
            a1c = __builtin_amdgcn_mfma_f32_16x16x32_f16(a, b1, a1c, 0, 0, 0);
        }
        // store Y (row = quad*4+rr, col = t*16+c15)
#pragma unroll
        for (int rr = 0; rr < 4; ++rr) {
            int row = row0 + quad * 4 + rr;
            if (row < N) {
                Y[(size_t)row * NOUT + t0 * 16 + c15] = (__half)a0c[rr];
                Y[(size_t)row * NOUT + (t0 + 1) * 16 + c15] = (__half)a1c[rr];
            }
        }
        // attention epilogue for head hd = t0/2
        int hd = t0 >> 1;
        float as0 = a_src[t0 * 16 + c15], as1 = a_src[(t0 + 1) * 16 + c15];
        float ad0 = a_dst[t0 * 16 + c15], ad1 = a_dst[(t0 + 1) * 16 + c15];
#pragma unroll
        for (int rr = 0; rr < 4; ++rr) {
            float s = a0c[rr] * as0 + a1c[rr] * as1;
            float dd = a0c[rr] * ad0 + a1c[rr] * ad1;
#pragma unroll
            for (int off = 8; off >= 1; off >>= 1) {
                s += __shfl_xor(s, off);
                dd += __shfl_xor(dd, off);
            }
            int row = row0 + quad * 4 + rr;
            if (row < N) {
                if (c15 == 0) es_o[row * HH + hd] = s;
                if (c15 == 1) ed_o[row * HH + hd] = dd;
            }
        }
    }
}

// ---------- layer 3: aggregate (D=32) + bias + LN + ELU + pool --------------
// 8 dsts per 64-lane wave: 8 lanes per dst (cl = lane&7), 4 channels each via
// uint2 (8 B) loads. 32 dsts per block.
__global__ __launch_bounds__(256) void aggr_ln32_pool_kernel(
    const int* __restrict__ rowptr, const int* __restrict__ csrc,
    const __half* __restrict__ h, const float* __restrict__ es,
    const float* __restrict__ ed, const float* __restrict__ bias,
    const float* __restrict__ gam, const float* __restrict__ bet,
    const int* __restrict__ batch, float* __restrict__ psum,
    unsigned* __restrict__ pmax, float* __restrict__ cnt, int N) {
    constexpr int D = 32;
    __shared__ float lsum[2][32];
    __shared__ unsigned lmax[2][32];
    __shared__ float lcnt[2];
    __shared__ int g0s;
    int tid = threadIdx.x;
    int d = (blockIdx.x * 256 + tid) >> 3;   // 8-lane group per dst
    int cl = tid & 7;
    int c = cl * 4;
    int dbase = blockIdx.x * 32;  // first node of this block
    if (tid < 64) {
        lsum[tid >> 5][tid & 31] = 0.f;
        lmax[tid >> 5][tid & 31] = 0u;
    }
    if (tid < 2) lcnt[tid] = 0.f;
    if (tid == 0) g0s = batch[dbase < N ? dbase : (N - 1)];
    __syncthreads();
    int g0 = g0s;
    if (d < N) {
        float edv = ed[d];
        float acc[4] = {0.f, 0.f, 0.f, 0.f};
        float l = 0.f;
        int k = rowptr[d], end = rowptr[d + 1];
        for (; k + 8 <= end; k += 8) {
            int s[8];
#pragma unroll
            for (int j = 0; j < 8; ++j) s[j] = csrc[k + j];
            float e[8];
#pragma unroll
            for (int j = 0; j < 8; ++j) e[j] = es[s[j]];
            uint2 u[8];
#pragma unroll
            for (int j = 0; j < 8; ++j)
                u[j] = *(const uint2*)(h + (size_t)s[j] * D + c);
#pragma unroll
            for (int j = 0; j < 8; ++j) {
                float w = __expf(lrelu(e[j] + edv));
                l += w;
                float2 f0 = __half22float2(*(__half2*)&u[j].x);
                float2 f1 = __half22float2(*(__half2*)&u[j].y);
                acc[0] += w * f0.x; acc[1] += w * f0.y;
                acc[2] += w * f1.x; acc[3] += w * f1.y;
            }
        }
        for (; k + 4 <= end; k += 4) {
            int s[4];
#pragma unroll
            for (int j = 0; j < 4; ++j) s[j] = csrc[k + j];
            float e[4];
#pragma unroll
            for (int j = 0; j < 4; ++j) e[j] = es[s[j]];
            uint2 u[4];
#pragma unroll
            for (int j = 0; j < 4; ++j)
                u[j] = *(const uint2*)(h + (size_t)s[j] * D + c);
#pragma unroll
            for (int j = 0; j < 4; ++j) {
                float w = __expf(lrelu(e[j] + edv));
                l += w;
                float2 f0 = __half22float2(*(__half2*)&u[j].x);
                float2 f1 = __half22float2(*(__half2*)&u[j].y);
                acc[0] += w * f0.x; acc[1] += w * f0.y;
                acc[2] += w * f1.x; acc[3] += w * f1.y;
            }
        }
        for (; k < end; ++k) {
            int s = csrc[k];
            float w = __expf(lrelu(es[s] + edv));
            uint2 u = *(const uint2*)(h + (size_t)s * D + c);
            l += w;
            float2 f0 = __half22float2(*(__half2*)&u.x);
            float2 f1 = __half22float2(*(__half2*)&u.y);
            acc[0] += w * f0.x; acc[1] += w * f0.y;
            acc[2] += w * f1.x; acc[3] += w * f1.y;
        }
        float rl = 1.f / (l + 1e-16f);
        float4 b4 = *(const float4*)(bias + c);
        float v0 = acc[0] * rl + b4.x;
        float v1 = acc[1] * rl + b4.y;
        float v2 = acc[2] * rl + b4.z;
        float v3 = acc[3] * rl + b4.w;
        float sm = v0 + v1 + v2 + v3;
        float ssum = v0 * v0 + v1 * v1 + v2 * v2 + v3 * v3;
#pragma unroll
        for (int off = 1; off <= 4; off <<= 1) {
            sm += __shfl_xor(sm, off);
            ssum += __shfl_xor(ssum, off);
        }
        float mean = sm / D;
        float var = ssum / D - mean * mean;
        float rstd = rsqrtf(var + 1e-5f);
        float4 g4 = *(const float4*)(gam + c);
        float4 t4 = *(const float4*)(bet + c);
        float o0 = (v0 - mean) * rstd * g4.x + t4.x;
        float o1 = (v1 - mean) * rstd * g4.y + t4.y;
        float o2 = (v2 - mean) * rstd * g4.z + t4.z;
        float o3 = (v3 - mean) * rstd * g4.w + t4.w;
        o0 = o0 > 0.f ? o0 : expm1f(o0);
        o1 = o1 > 0.f ? o1 : expm1f(o1);
        o2 = o2 > 0.f ? o2 : expm1f(o2);
        o3 = o3 > 0.f ? o3 : expm1f(o3);
        int g = batch[d];
        int goff = g - g0;
        if (goff >= 0 && goff < 2) {
            atomicAdd(&lsum[goff][c + 0], o0);
            atomicAdd(&lsum[goff][c + 1], o1);
            atomicAdd(&lsum[goff][c + 2], o2);
            atomicAdd(&lsum[goff][c + 3], o3);
            atomicMax(&lmax[goff][c + 0], encf(o0));
            atomicMax(&lmax[goff][c + 1], encf(o1));
            atomicMax(&lmax[goff][c + 2], encf(o2));
            atomicMax(&lmax[goff][c + 3], encf(o3));
            if (cl == 0) atomicAdd(&lcnt[goff], 1.0f);
        } else {
            atomicAdd(&psum[g * D + c + 0], o0);
            atomicAdd(&psum[g * D + c + 1], o1);
            atomicAdd(&psum[g * D + c + 2], o2);
            atomicAdd(&psum[g * D + c + 3], o3);
            atomicMax(&pmax[g * D + c + 0], encf(o0));
            atomicMax(&pmax[g * D + c + 1], encf(o1));
            atomicMax(&pmax[g * D + c + 2], encf(o2));
            atomicMax(&pmax[g * D + c + 3], encf(o3));
            if (cl == 0) atomicAdd(&cnt[g], 1.0f);
        }
    }
    __syncthreads();
    if (tid < 64) {
        int go = tid >> 5, cc = tid & 31;
        unsigned m = lmax[go][cc];
        if (m != 0u) {
            int gg = g0 + go;
            atomicAdd(&psum[gg * D + cc], lsum[go][cc]);
            atomicMax(&pmax[gg * D + cc], m);
            if (cc == 0) atomicAdd(&cnt[gg], lcnt[go]);
        }
    }
}

// ---------- fallback aggregation (online softmax, generic shapes) -----------
__global__ __launch_bounds__(256) void aggr_csr_kernel(
    const int* __restrict__ rowptr, const int* __restrict__ csrc,
    const float* __restrict__ h, const float* __restrict__ es,
    const float* __restrict__ ed, float* __restrict__ outp, int N, int H,
    int C) {
    int D = H * C;
    int wave = (blockIdx.x * blockDim.x + threadIdx.x) >> 6;
    int lane = threadIdx.x & 63;
    if (wave >= N) return;
    int d = wave;
    int c0 = lane, c1 = lane + 64;
    bool a0 = c0 < D, a1 = c1 < D;
    int h0 = a0 ? c0 / C : 0;
    int h1 = a1 ? c1 / C : 0;
    float edv0 = a0 ? ed[d * H + h0] : 0.f;
    float edv1 = a1 ? ed[d * H + h1] : 0.f;
    float m0 = -INFINITY, m1 = -INFINITY;
    float l0 = 0.f, l1 = 0.f, acc0 = 0.f, acc1 = 0.f;
    int beg = rowptr[d], end = rowptr[d + 1];
    for (int k = beg; k < end; ++k) {
        int s = csrc[k];
        const float* hp = h + (size_t)s * D;
        if (a0) {
            float v = lrelu(es[s * H + h0] + edv0);
            float nm = fmaxf(m0, v);
            float sc = __expf(m0 - nm);
            float w = __expf(v - nm);
            l0 = l0 * sc + w;
            acc0 = acc0 * sc + w * hp[c0];
            m0 = nm;
        }
        if (a1) {
            float v = lrelu(es[s * H + h1] + edv1);
            float nm = fmaxf(m1, v);
            float sc = __expf(m1 - nm);
            float w = __expf(v - nm);
            l1 = l1 * sc + w;
            acc1 = acc1 * sc + w * hp[c1];
            m1 = nm;
        }
    }
    if (a0) outp[(size_t)d * D + c0] = acc0 / (l0 + 1e-16f);
    if (a1) outp[(size_t)d * D + c1] = acc1 / (l1 + 1e-16f);
}

// ---------- bias + LayerNorm + ELU (fallback path) --------------------------
__global__ __launch_bounds__(64) void ln_elu_kernel(
    const float* __restrict__ in, const float* __restrict__ bias,
    const float* __restrict__ gam, const float* __restrict__ bet,
    float* __restrict__ outp, int D) {
    int n = blockIdx.x;
    int lane = threadIdx.x;  // blockDim = 64
    int c0 = lane, c1 = lane + 64;
    bool a0 = c0 < D, a1 = c1 < D;
    float v0 = 0.f, v1 = 0.f;
    if (a0) v0 = in[(size_t)n * D + c0] + bias[c0];
    if (a1) v1 = in[(size_t)n * D + c1] + bias[c1];
    float s = v0 + v1;
    float ss = v0 * v0 + v1 * v1;
    for (int off = 32; off; off >>= 1) {
        s += __shfl_xor(s, off);
        ss += __shfl_xor(ss, off);
    }
    float mean = s / D;
    float var = ss / D - mean * mean;
    float rstd = rsqrtf(var + 1e-5f);
    if (a0) {
        float o = (v0 - mean) * rstd * gam[c0] + bet[c0];
        outp[(size_t)n * D + c0] = o > 0.f ? o : expm1f(o);
    }
    if (a1) {
        float o = (v1 - mean) * rstd * gam[c1] + bet[c1];
        outp[(size_t)n * D + c1] = o > 0.f ? o : expm1f(o);
    }
}

// ---------- graph pooling (fallback path) -----------------------------------
__global__ __launch_bounds__(256) void pool_kernel(
    const float* __restrict__ h, const int* __restrict__ batch, int N, int C,
    float* __restrict__ psum, unsigned* __restrict__ pmax,
    float* __restrict__ cnt) {
    int idx = blockIdx.x * blockDim.x + threadIdx.x;
    if (idx >= N * C) return;
    int n = idx / C;
    int c = idx - n * C;
    int g = batch[n];
    float v = h[(size_t)n * C + c];
    atomicAdd(&psum[g * C + c], v);
    atomicMax(&pmax[g * C + c], encf(v));
    if (c == 0) atomicAdd(&cnt[g], 1.0f);
}

// ---------- classifier MLP: one block (1 wave) per graph --------------------
__global__ __launch_bounds__(64) void mlp_kernel(
    const float* __restrict__ psum, const unsigned* __restrict__ pmax,
    const float* __restrict__ cnt, const float* __restrict__ cW1,
    const float* __restrict__ cb1, const float* __restrict__ cW2,
    const float* __restrict__ cb2, const float* __restrict__ cW3,
    const float* __restrict__ cb3, float* __restrict__ outp, int C) {
    __shared__ float f[64];
    __shared__ float t1[32];
    __shared__ float t2[16];
    int g = blockIdx.x;
    int t = threadIdx.x;
    float c = fmaxf(cnt[g], 1.0f);
    if (t < C) {
        f[t] = psum[g * C + t] / c;
    } else if (t < 2 * C) {
        unsigned k = pmax[g * C + (t - C)];
        f[t] = (k == 0u) ? -INFINITY : decf(k);
    }
    __syncthreads();
    if (t < 32) {
        float a = cb1[t];
        for (int i = 0; i < 64; ++i) a += f[i] * cW1[t * 64 + i];
        t1[t] = fmaxf(a, 0.f);
    }
    __syncthreads();
    if (t < 16) {
        float a = cb2[t];
        for (int i = 0; i < 32; ++i) a += t1[i] * cW2[t * 32 + i];
        t2[t] = fmaxf(a, 0.f);
    }
    __syncthreads();
    if (t == 0) {
        float a = cb3[0];
        for (int i = 0; i < 16; ++i) a += t2[i] * cW3[i];
        outp[g] = a;
    }
}

// ---------------------------------------------------------------------------
extern "C" void kernel_launch(void* const* d_in, const int* in_sizes, int n_in,
                              void* d_out, int out_size, void* d_ws,
                              size_t ws_size, hipStream_t stream) {
    const float* x = (const float*)d_in[0];
    const int* ei = (const int*)d_in[1];
    const int* batch = (const int*)d_in[2];
    const float* W1 = (const float*)d_in[4];
    const float* as1 = (const float*)d_in[5];
    const float* ad1 = (const float*)d_in[6];
    const float* b1 = (const float*)d_in[7];
    const float* g1 = (const float*)d_in[8];
    const float* be1 = (const float*)d_in[9];
    const float* W2 = (const float*)d_in[10];
    const float* as2 = (const float*)d_in[11];
    const float* ad2 = (const float*)d_in[12];
    const float* b2 = (const float*)d_in[13];
    const float* g2 = (const float*)d_in[14];
    const float* be2 = (const float*)d_in[15];
    const float* W3 = (const float*)d_in[16];
    const float* as3 = (const float*)d_in[17];
    const float* ad3 = (const float*)d_in[18];
    const float* b3 = (const float*)d_in[19];
    const float* g3 = (const float*)d_in[20];
    const float* be3 = (const float*)d_in[21];
    const float* cW1 = (const float*)d_in[22];
    const float* cb1 = (const float*)d_in[23];
    const float* cW2 = (const float*)d_in[24];
    const float* cb2 = (const float*)d_in[25];
    const float* cW3 = (const float*)d_in[26];
    const float* cb3 = (const float*)d_in[27];

    const int N = in_sizes[2];            // 50000
    const int E = in_sizes[1] / 2;        // 800000
    const int F0 = in_sizes[0] / N;       // 32
    const int Hd = in_sizes[19];          // 32 (b3)
    const int H = in_sizes[5] / Hd;       // 4
    const int D = H * Hd;                 // 128
    const int H3 = in_sizes[17] / Hd;     // 1
    const int G = out_size;               // 512
    const int EN = E + N;
    const bool shapes_ok = (F0 == 32 && Hd == 32 && H == 4 && D == 128 &&
                            H3 == 1 && N <= 65536);

    // -------- workspace carve-out (256B aligned) --------
    char* w = (char*)d_ws;
    size_t off = 0;
    auto carve = [&](size_t bytes) -> void* {
        void* p = w + off;
        off = (off + bytes + 255) & ~(size_t)255;
        return p;
    };
    float* Q = (float*)carve((size_t)N * D * 4);      // fallback fp32 staging
    __half* Qh = (__half*)Q;                          // main path fp16 h1/h3
    float* R = (float*)carve((size_t)N * D * 4);      // fallback scratch
    float* P = (float*)carve((size_t)N * D * 4);      // fallback activations
    __half* Ph = (__half*)P;                          // main path fp16 h2
    float* es1 = (float*)carve((size_t)N * H * 4);
    float* ed1 = (float*)carve((size_t)N * H * 4);
    float* es2 = (float*)carve((size_t)N * H * 4);
    float* ed2 = (float*)carve((size_t)N * H * 4);
    int* rowptr = (int*)carve((size_t)(N + 1) * 4);
    int* cursor = (int*)carve((size_t)N * 4);
    int* csrc = (int*)carve((size_t)EN * 4);
    int* bsum = (int*)carve((size_t)CDIV(N, SCAN_BS) * 4);
    const int nblkA = CDIV(E, ATILE);
    int* ghist = (int*)carve((size_t)nblkA * NBUK * 4);
    int* tot = (int*)carve((size_t)NBUK * 4);
    unsigned* ebuf = (unsigned*)carve((size_t)E * 4);
    __half* wh2 = (__half*)carve((size_t)8 * 4 * 64 * 8 * 2);
    __half* wh3 = (__half*)carve((size_t)2 * 4 * 64 * 8 * 2);
    // psum/pmax/cnt carved contiguously (sizes are 256B multiples) so one
    // zero-fill covers all three.
    float* psum = (float*)carve((size_t)G * Hd * 4);
    unsigned* pmax = (unsigned*)carve((size_t)G * Hd * 4);
    float* cnt = (float*)carve((size_t)G * 4);
    (void)ws_size;
    (void)n_in;

    const int BLK = 256;
    const int nb = CDIV(N, SCAN_BS);
    const int poolInts = G * Hd * 2 + G;  // psum + pmax + cnt (ints)

    if (shapes_ok) {
        // ---- bucketed CSR build; binA1 also zero-fills pooling buffers,
        //      runs wh2/wh3 swizzles (10 blocks) AND the full layer-1
        //      GEMM+attn (inline W1->LDS swizzle) as extra block ranges ----
        const int nwp = 10;                  // 2560 threads for wh2+wh3
        const int ngemm1 = CDIV(N, 64);
        binA1_kernel<<<nblkA + nwp + ngemm1, 256, 0, stream>>>(
            ei, E, ghist, (int*)psum, poolInts, W1, W2, W3, wh2, wh3,
            rowptr, N, nblkA, nwp, x, Qh, as1, ad1, es1, ed1);
        binA2a_kernel<<<NBUK, 64, 0, stream>>>(ghist, tot, nblkA);
        binA3_kernel<<<nblkA, 256, 0, stream>>>(ei, E, ghist, tot, ebuf);
        binB_kernel<<<CDIV(N, 128), 256, 0, stream>>>(ebuf, tot, rowptr,
                                                      csrc, N);
        // fused: layer-1 aggregation + LN + ELU -> LDS -> layer-2 GEMM+attn
        // reads h1=Qh,es1/ed1; writes h2=Ph,es2/ed2 (disjoint buffers)
        aggr_gemm_kernel<128, 4><<<CDIV(N, 16), 256, 0, stream>>>(
            rowptr, csrc, Qh, es1, ed1, b1, g1, be1, wh2, Ph, as2, ad2,
            es2, ed2, N);
        // fused: layer-2 aggregation + LN + ELU -> LDS -> layer-3 GEMM+attn
        // reads h2=Ph,es2/ed2; writes h3=Qh (N x 32 fp16), es1/ed1 (N x 1)
        aggr_gemm_kernel<32, 1><<<CDIV(N, 16), 256, 0, stream>>>(
            rowptr, csrc, Ph, es2, ed2, b2, g2, be2, wh3, Qh, as3, ad3,
            es1, ed1, N);
        // layer 3 aggregation (+ fused pooling)
        aggr_ln32_pool_kernel<<<CDIV(N, 32), 256, 0, stream>>>(
            rowptr, csrc, Qh, es1, ed1, b3, g3, be3, batch, psum, pmax,
            cnt, N);
    } else {
        // generic fallback path (all fp32, plain CSR build)
        float* es = es1;
        float* ed = ed1;
        hipMemsetAsync(psum, 0, (size_t)G * Hd * 4, stream);
        hipMemsetAsync(pmax, 0, (size_t)G * Hd * 4, stream);
        hipMemsetAsync(cnt, 0, (size_t)G * 4, stream);
        hipMemsetAsync(cursor, 0, (size_t)N * 4, stream);
        deg_kernel<<<CDIV(E, BLK), BLK, 0, stream>>>(ei, E, cursor);
        scan1_kernel<<<nb, SCAN_BS, 0, stream>>>(cursor, rowptr, bsum, N);
        scan2_kernel<<<1, 64, 0, stream>>>(bsum, nb);
        scan3_kernel<<<nb, SCAN_BS, 0, stream>>>(rowptr, cursor, csrc, bsum, N, EN);
        scatter_kernel<<<CDIV(E, BLK), BLK, 0, stream>>>(ei, E, cursor, csrc);
        gemm_kernel<<<CDIV(N * D, BLK), BLK, 0, stream>>>(x, W1, Q, N, F0, D);
        attn_kernel<<<CDIV(N * H, BLK), BLK, 0, stream>>>(Q, as1, ad1, es, ed, N, H, Hd);
        aggr_csr_kernel<<<CDIV(N, 4), BLK, 0, stream>>>(rowptr, csrc, Q, es, ed, R, N, H, Hd);
        ln_elu_kernel<<<N, 64, 0, stream>>>(R, b1, g1, be1, P, D);
        gemm_kernel<<<CDIV(N * D, BLK), BLK, 0, stream>>>(P, W2, Q, N, D, D);
        attn_kernel<<<CDIV(N * H, BLK), BLK, 0, stream>>>(Q, as2, ad2, es, ed, N, H, Hd);
        aggr_csr_kernel<<<CDIV(N, 4), BLK, 0, stream>>>(rowptr, csrc, Q, es, ed, R, N, H, Hd);
        ln_elu_kernel<<<N, 64, 0, stream>>>(R, b2, g2, be2, P, D);
        gemm_kernel<<<CDIV(N * Hd, BLK), BLK, 0, stream>>>(P, W3, Q, N, D, Hd);
        attn_kernel<<<CDIV(N * H3, BLK), BLK, 0, stream>>>(Q, as3, ad3, es, ed, N, H3, Hd);
        aggr_csr_kernel<<<CDIV(N, 4), BLK, 0, stream>>>(rowptr, csrc, Q, es, ed, R, N, H3, Hd);
        ln_elu_kernel<<<N, 64, 0, stream>>>(R, b3, g3, be3, P, Hd);
        pool_kernel<<<CDIV(N * Hd, BLK), BLK, 0, stream>>>(P, batch, N, Hd, psum, pmax, cnt);
    }

    mlp_kernel<<<G, 64, 0, stream>>>(psum, pmax, cnt, cW1, cb1, cW2, cb2, cW3,
                                     cb3, (float*)d_out, Hd);
}

// Round 10
// 261.729 us; speedup vs baseline: 1.5175x; 1.0049x over previous
//
#include <hip/hip_runtime.h>
#include <hip/hip_fp16.h>
#include <math.h>

#define CDIV(a, b) (((a) + (b) - 1) / (b))
#define SCAN_BS 1024
#define NBUK 512          // dst buckets (dst>>7); covers N <= 65536
#define ATILE 4096        // edges per Stage-A block

typedef _Float16 f16x8 __attribute__((ext_vector_type(8)));
typedef float f32x4 __attribute__((ext_vector_type(4)));

// ---------- float <-> monotone-unsigned encoding for atomicMax on floats ----
__device__ __forceinline__ unsigned encf(float v) {
    unsigned u = __float_as_uint(v);
    return (u & 0x80000000u) ? ~u : (u | 0x80000000u);
}
__device__ __forceinline__ float decf(unsigned k) {
    unsigned u = (k & 0x80000000u) ? (k ^ 0x80000000u) : ~k;
    return __uint_as_float(u);
}

__device__ __forceinline__ float lrelu(float v) {
    return v > 0.f ? v : 0.2f * v;
}

// ---------- naive GEMM fallback (only if shapes are unexpected) -------------
__global__ __launch_bounds__(256) void gemm_kernel(
    const float* __restrict__ X, const float* __restrict__ W,
    float* __restrict__ Y, int M, int K, int Nout) {
    int idx = blockIdx.x * blockDim.x + threadIdx.x;
    if (idx >= M * Nout) return;
    int row = idx / Nout;
    int col = idx - row * Nout;
    const float* xr = X + (size_t)row * K;
    const float* wc = W + col;
    float acc = 0.f;
    for (int k = 0; k < K; k += 4) {
        float4 xv = *(const float4*)(xr + k);
        acc += xv.x * wc[(size_t)(k + 0) * Nout];
        acc += xv.y * wc[(size_t)(k + 1) * Nout];
        acc += xv.z * wc[(size_t)(k + 2) * Nout];
        acc += xv.w * wc[(size_t)(k + 3) * Nout];
    }
    Y[idx] = acc;
}

// ---------- weight prep: swizzle W (K x NOUT fp32) into B-fragment order ----
__device__ __forceinline__ void wprep_one(const float* __restrict__ W,
                                          __half* __restrict__ Whf, int K,
                                          int NOUT, int idx) {
    int NK = K / 32;
    int l = idx & 63, f = idx >> 6;
    int ks = f % NK, tt = f / NK;
    int quad = l >> 4, c15 = l & 15;
    _Float16 v[8];
#pragma unroll
    for (int j = 0; j < 8; ++j) {
        int k = ks * 32 + quad * 8 + j;
        int n = tt * 16 + c15;
        v[j] = (_Float16)W[(size_t)k * NOUT + n];
    }
    *(uint4*)(Whf + (size_t)idx * 8) = *(uint4*)v;
}

// LDS-destination variant (same math; generic-pointer store works for LDS)
__device__ __forceinline__ void wprep_one_lds(const float* __restrict__ W,
                                              __half* Whf, int K, int NOUT,
                                              int idx) {
    int NK = K / 32;
    int l = idx & 63, f = idx >> 6;
    int ks = f % NK, tt = f / NK;
    int quad = l >> 4, c15 = l & 15;
    _Float16 v[8];
#pragma unroll
    for (int j = 0; j < 8; ++j) {
        int k = ks * 32 + quad * 8 + j;
        int n = tt * 16 + c15;
        v[j] = (_Float16)W[(size_t)k * NOUT + n];
    }
    *(uint4*)(Whf + (size_t)idx * 8) = *(uint4*)v;
}

// ---------- A-fragment loaders ----------------------------------------------
__device__ __forceinline__ f16x8 loadA(const float* p) {
    float4 lo = *(const float4*)p;
    float4 hi = *(const float4*)(p + 4);
    f16x8 a;
    a[0] = (_Float16)lo.x; a[1] = (_Float16)lo.y;
    a[2] = (_Float16)lo.z; a[3] = (_Float16)lo.w;
    a[4] = (_Float16)hi.x; a[5] = (_Float16)hi.y;
    a[6] = (_Float16)hi.z; a[7] = (_Float16)hi.w;
    return a;
}
__device__ __forceinline__ f16x8 loadA(const __half* p) {
    return *(const f16x8*)p;
}

// ---------- MFMA GEMM + fused attention-coefficient epilogue (body) ---------
// Y[M,NOUT] (fp16) = X[M,K] @ B-fragments bp; es/ed[M,HH] from the fp32
// accumulators (head h covers channels [32h,32h+32) = tiles 2h,2h+1).
template <int K, int NOUT, int HH, typename XT, typename BP>
__device__ __forceinline__ void gemm_attn_body(
    const XT* __restrict__ X, const BP* bp, __half* __restrict__ Y,
    const float* __restrict__ a_src, const float* __restrict__ a_dst,
    float* __restrict__ es, float* __restrict__ ed, int M, int blk) {
    constexpr int NK = K / 32, NT = NOUT / 16;
    static_assert(NT == 2 * HH, "32 channels per head assumed");
    int wave = threadIdx.x >> 6, lane = threadIdx.x & 63;
    int quad = lane >> 4, c15 = lane & 15;
    int row0 = (blk * 4 + wave) * 16;
    if (row0 >= M) return;  // uniform per wave
    int arow = row0 + c15;
    if (arow >= M) arow = M - 1;
    const XT* xr = X + (size_t)arow * K + quad * 8;
    f32x4 acc[NT];
#pragma unroll
    for (int t = 0; t < NT; ++t) {
        acc[t][0] = 0.f; acc[t][1] = 0.f; acc[t][2] = 0.f; acc[t][3] = 0.f;
    }
#pragma unroll
    for (int ks = 0; ks < NK; ++ks) {
        f16x8 a = loadA(xr + ks * 32);
#pragma unroll
        for (int t = 0; t < NT; ++t) {
            f16x8 b = *(const f16x8*)&bp[((t * NK + ks) * 64 + lane) * 8];
            acc[t] = __builtin_amdgcn_mfma_f32_16x16x32_f16(a, b, acc[t],
                                                            0, 0, 0);
        }
    }
    // store Y (C/D mapping: row = quad*4+r, col = t*16+c15)
#pragma unroll
    for (int r = 0; r < 4; ++r) {
        int row = row0 + quad * 4 + r;
        if (row < M) {
#pragma unroll
            for (int t = 0; t < NT; ++t)
                Y[(size_t)row * NOUT + t * 16 + c15] = (__half)acc[t][r];
        }
    }
    // attention epilogue: es[row,h] = sum_c Y[row,32h+c]*a_src[32h+c]
    float asv[NT], adv[NT];
#pragma unroll
    for (int t = 0; t < NT; ++t) {
        asv[t] = a_src[t * 16 + c15];
        adv[t] = a_dst[t * 16 + c15];
    }
#pragma unroll
    for (int h = 0; h < HH; ++h) {
#pragma unroll
        for (int r = 0; r < 4; ++r) {
            float s = acc[2 * h][r] * asv[2 * h] +
                      acc[2 * h + 1][r] * asv[2 * h + 1];
            float dd = acc[2 * h][r] * adv[2 * h] +
                       acc[2 * h + 1][r] * adv[2 * h + 1];
#pragma unroll
            for (int off = 8; off >= 1; off >>= 1) {
                s += __shfl_xor(s, off);     // stays inside the 16-lane quad
                dd += __shfl_xor(dd, off);
            }
            int row = row0 + quad * 4 + r;
            if (row < M) {
                if (c15 == 0) es[row * HH + h] = s;
                if (c15 == 1) ed[row * HH + h] = dd;
            }
        }
    }
}

// ============ Bucketed CSR build ============================================
// Stage A1: per-block bucket histogram (bucket = dst>>7). Side jobs folded in:
//   - zero-fills the pooling buffers (replaces 3 hipMemsetAsync dispatches)
//   - blocks [nhist, nhist+nwp): wh2/wh3 weight swizzles + rowptr[N] sentinel
//   - blocks >= nhist+nwp: layer-1 GEMM+attn with inline W1->LDS swizzle
//     (gemm1 has no CSR dependency; overlaps with the histogram phase)
__global__ __launch_bounds__(256) void binA1_kernel(
    const int* __restrict__ ei, int E, int* __restrict__ ghist,
    int* __restrict__ pool0, int poolN, const float* __restrict__ W1,
    const float* __restrict__ W2, const float* __restrict__ W3,
    __half* __restrict__ wh2, __half* __restrict__ wh3,
    int* __restrict__ rowptr, int N, int nhist, int nwp,
    const float* __restrict__ x, __half* __restrict__ Qh,
    const float* __restrict__ as1, const float* __restrict__ ad1,
    float* __restrict__ es, float* __restrict__ ed) {
    __shared__ int lh[NBUK];
    __shared__ __half wlds[512 * 8];   // 8 KB: W1 fragments for gemm1 blocks
    int t = threadIdx.x;
    if (blockIdx.x >= nhist + nwp) {   // ---- gemm1 blocks ----
        for (int i = t; i < 512; i += 256)
            wprep_one_lds(W1, wlds, 32, 128, i);
        __syncthreads();
        gemm_attn_body<32, 128, 4>(x, wlds, Qh, as1, ad1, es, ed, N,
                                   blockIdx.x - nhist - nwp);
        return;
    }
    if (blockIdx.x >= nhist) {         // ---- weight-prep blocks (wh2/wh3) --
        int idx = (blockIdx.x - nhist) * 256 + t;
        if (idx == 0) rowptr[N] = E + N;
        if (idx < 2048) {
            wprep_one(W2, wh2, 128, 128, idx);         // 8*4*64 = 2048
        } else if (idx < 2560) {
            wprep_one(W3, wh3, 128, 32, idx - 2048);   // 2*4*64 = 512
        }
        return;
    }
    int gid = blockIdx.x * 256 + t;
    if (gid < poolN) pool0[gid] = 0;
    for (int i = t; i < NBUK; i += 256) lh[i] = 0;
    __syncthreads();
    int base = blockIdx.x * ATILE;
#pragma unroll 4
    for (int j = 0; j < ATILE / 256; ++j) {
        int idx = base + t + 256 * j;
        if (idx < E) atomicAdd(&lh[ei[E + idx] >> 7], 1);
    }
    __syncthreads();
    int* gh = ghist + (size_t)blockIdx.x * NBUK;
    for (int i = t; i < NBUK; i += 256) gh[i] = lh[i];
}

// Stage A2: one wave per bucket — exclusive prefix over blocks (column scan)
__global__ __launch_bounds__(64) void binA2a_kernel(
    int* __restrict__ ghist, int* __restrict__ tot, int nblk) {
    int b = blockIdx.x;
    int lane = threadIdx.x;
    int accb = 0;
    for (int chunk = 0; chunk < nblk; chunk += 64) {
        int i = chunk + lane;
        int v = (i < nblk) ? ghist[(size_t)i * NBUK + b] : 0;
        int s = v;
        for (int off = 1; off < 64; off <<= 1) {
            int tv = __shfl_up(s, off);
            if (lane >= off) s += tv;
        }
        if (i < nblk) ghist[(size_t)i * NBUK + b] = s - v + accb;  // exclusive
        accb += __shfl(s, 63);
    }
    if (lane == 0) tot[b] = accb;
}

// in-block exclusive scan over tot[NBUK] (256 threads, 2 elems each).
// On return: excl = prefix of element 2t; a0/a1 = tot[2t], tot[2t+1].
__device__ __forceinline__ void bucketScan(const int* __restrict__ tot,
                                           int* __restrict__ sc, int t,
                                           int& a0, int& a1, int& excl) {
    a0 = tot[2 * t];
    a1 = tot[2 * t + 1];
    int pair = a0 + a1;
    sc[t] = pair;
    __syncthreads();
#pragma unroll
    for (int off = 1; off < 256; off <<= 1) {
        int v = (t >= off) ? sc[t - off] : 0;
        __syncthreads();
        sc[t] += v;
        __syncthreads();
    }
    excl = sc[t] - pair;
}

// Stage A3: binned scatter of packed (dst<<16)|src into bucket-contiguous ebuf
// (bucket base offsets recomputed in-block from tot — no binA2b dispatch).
__global__ __launch_bounds__(256) void binA3_kernel(
    const int* __restrict__ ei, int E, const int* __restrict__ ghist,
    const int* __restrict__ tot, unsigned* __restrict__ ebuf) {
    __shared__ int lcur[NBUK];
    __shared__ int sc[256];
    int t = threadIdx.x;
    int a0, a1, excl;
    bucketScan(tot, sc, t, a0, a1, excl);
    const int* gh = ghist + (size_t)blockIdx.x * NBUK;
    lcur[2 * t] = gh[2 * t] + excl;
    lcur[2 * t + 1] = gh[2 * t + 1] + excl + a0;
    __syncthreads();
    int base = blockIdx.x * ATILE;
#pragma unroll 4
    for (int j = 0; j < ATILE / 256; ++j) {
        int idx = base + t + 256 * j;
        if (idx < E) {
            int s = ei[idx];
            int d = ei[E + idx];
            int pos = atomicAdd(&lcur[d >> 7], 1);
            ebuf[pos] = ((unsigned)d << 16) | (unsigned)s;
        }
    }
}

// Stage B: one block per bucket — local degree histogram + prefix gives
// rowptr (contiguous write) and the final CSR scatter into this bucket's
// private csrc region. Bucket range recomputed in-block from tot.
__global__ __launch_bounds__(256) void binB_kernel(
    const unsigned* __restrict__ ebuf, const int* __restrict__ tot,
    int* __restrict__ rowptr, int* __restrict__ csrc, int N) {
    __shared__ int cnt_[128];
    __shared__ int pre[128];
    __shared__ int lcur[128];
    __shared__ int sc[256];
    __shared__ int begS;
    int b = blockIdx.x;
    int t = threadIdx.x;
    int n0 = b << 7;
    int totb = tot[b];
    if (t < 128) cnt_[t] = 0;
    int a0, a1, excl;
    bucketScan(tot, sc, t, a0, a1, excl);
    if (t == (b >> 1)) begS = (b & 1) ? (excl + a0) : excl;
    __syncthreads();
    int beg = begS, end = begS + totb;
    for (int i = beg + t; i < end; i += 256)
        atomicAdd(&cnt_[(ebuf[i] >> 16) - n0], 1);
    __syncthreads();
    // inclusive scan of (cnt+1 if node valid else 0) over 128 entries
    if (t < 128) pre[t] = (n0 + t < N) ? (cnt_[t] + 1) : 0;
    __syncthreads();
    for (int off = 1; off < 128; off <<= 1) {
        int v = 0;
        if (t < 128 && t >= off) v = pre[t - off];
        __syncthreads();
        if (t < 128) pre[t] += v;
        __syncthreads();
    }
    int cbase = beg + n0;  // edges before bucket + self-loop slots before it
    if (t < 128 && n0 + t < N) {
        int ex = pre[t] - (cnt_[t] + 1);
        int rp = cbase + ex;
        rowptr[n0 + t] = rp;
        csrc[rp] = n0 + t;   // self-loop in slot 0
        lcur[t] = rp + 1;
    }
    __syncthreads();
    for (int i = beg + t; i < end; i += 256) {
        unsigned e = ebuf[i];
        int d = (int)(e >> 16) - n0;
        int s = (int)(e & 0xFFFFu);
        int pos = atomicAdd(&lcur[d], 1);
        csrc[pos] = s;
    }
}

// ---------- attention coefficients (fallback path, fp32) --------------------
__global__ __launch_bounds__(256) void attn_kernel(
    const float* __restrict__ h, const float* __restrict__ a_src,
    const float* __restrict__ a_dst, float* __restrict__ es,
    float* __restrict__ ed, int N, int H, int C) {
    int idx = blockIdx.x * blockDim.x + threadIdx.x;
    if (idx >= N * H) return;
    int n = idx / H;
    int hh = idx - n * H;
    const float* hp = h + (size_t)n * H * C + (size_t)hh * C;
    const float* ap = a_src + hh * C;
    const float* bp = a_dst + hh * C;
    float s = 0.f, d = 0.f;
    for (int c = 0; c < C; c += 4) {
        float4 hv = *(const float4*)(hp + c);
        float4 av = *(const float4*)(ap + c);
        float4 bv = *(const float4*)(bp + c);
        s += hv.x * av.x + hv.y * av.y + hv.z * av.z + hv.w * av.w;
        d += hv.x * bv.x + hv.y * bv.y + hv.z * bv.z + hv.w * bv.w;
    }
    es[idx] = s;
    ed[idx] = d;
}

// ---------- fallback CSR build (generic shapes) -----------------------------
__global__ __launch_bounds__(256) void deg_kernel(const int* __restrict__ ei,
                                                  int E,
                                                  int* __restrict__ deg) {
    int e = blockIdx.x * blockDim.x + threadIdx.x;
    if (e >= E) return;
    atomicAdd(&deg[ei[E + e]], 1);
}

__global__ __launch_bounds__(SCAN_BS) void scan1_kernel(
    const int* __restrict__ deg, int* __restrict__ rowptr,
    int* __restrict__ bsum, int N) {
    __shared__ int tmp[SCAN_BS];
    int tid = threadIdx.x;
    int gid = blockIdx.x * SCAN_BS + tid;
    int v = (gid < N) ? (deg[gid] + 1) : 0;
    tmp[tid] = v;
    __syncthreads();
    for (int off = 1; off < SCAN_BS; off <<= 1) {
        int t = (tid >= off) ? tmp[tid - off] : 0;
        __syncthreads();
        tmp[tid] += t;
        __syncthreads();
    }
    if (gid < N) rowptr[gid] = tmp[tid] - v;
    if (tid == SCAN_BS - 1) bsum[blockIdx.x] = tmp[tid];
}

__global__ void scan2_kernel(int* __restrict__ bsum, int nb) {
    if (threadIdx.x == 0 && blockIdx.x == 0) {
        int acc = 0;
        for (int i = 0; i < nb; ++i) {
            int t = bsum[i];
            bsum[i] = acc;
            acc += t;
        }
    }
}

__global__ __launch_bounds__(SCAN_BS) void scan3_kernel(
    int* __restrict__ rowptr, int* __restrict__ cursor,
    int* __restrict__ csrc, const int* __restrict__ bsum, int N, int total) {
    int gid = blockIdx.x * SCAN_BS + threadIdx.x;
    if (gid < N) {
        int v = rowptr[gid] + bsum[blockIdx.x];
        rowptr[gid] = v;
        cursor[gid] = v + 1;
        csrc[v] = gid;
    }
    if (gid == 0) rowptr[N] = total;
}

__global__ __launch_bounds__(256) void scatter_kernel(
    const int* __restrict__ ei, int E, int* __restrict__ cursor,
    int* __restrict__ csrc) {
    int e = blockIdx.x * blockDim.x + threadIdx.x;
    if (e >= E) return;
    int s = ei[e];
    int d = ei[E + e];
    int pos = atomicAdd(&cursor[d], 1);
    csrc[pos] = s;
}

// ====== FUSED: softmax-aggregate + bias + LN + ELU -> LDS -> next GEMM ======
// 32 dsts per block. Phase 1: each 16-lane group walks TWO dsts sequentially
// (rows g and g+16) with the verified serial 8-edge-batch walk — the barrier
// waits on max of 16 PAIR-SUMS instead of max of 16 degrees (straggler
// inflation 1.6x -> ~1.38x). Phase 2: two 16-row MFMA A-tiles; for NOUT=128
// each wave processes both A-tiles sequentially (accs not live concurrently,
// keeping VGPR under the 64 cliff); for NOUT=32, A-tile w -> wave w.
template <int NOUT, int HH>
__global__ __launch_bounds__(256) void aggr_gemm_kernel(
    const int* __restrict__ rowptr, const int* __restrict__ csrc,
    const __half* __restrict__ h, const float* __restrict__ es,
    const float* __restrict__ ed, const float* __restrict__ bias,
    const float* __restrict__ gam, const float* __restrict__ bet,
    const __half* __restrict__ Whf, __half* __restrict__ Y,
    const float* __restrict__ a_src, const float* __restrict__ a_dst,
    float* __restrict__ es_o, float* __restrict__ ed_o, int N) {
    constexpr int D = 128, H = 4;          // aggregation-side geometry
    constexpr int NK = 4, NT = NOUT / 16;  // GEMM K = 128
    static_assert(NT == 2 * HH, "32 channels per head assumed");
    __shared__ __half lds[32][136];        // 32 rows, 128 + 8 pad (fp16)
    int tid = threadIdx.x;
    int grp = tid >> 4;                    // group 0..15
    int cl = tid & 15;
    int c = cl * 8;
    int hh = cl >> 2;                      // head = c/32
    int d0 = blockIdx.x * 32;
    // -------- phase 1: two dsts per group, sequential serial walks --------
#pragma unroll
    for (int pp = 0; pp < 2; ++pp) {
        int r = grp + 16 * pp;             // block-local row 0..31
        int d = d0 + r;
        if (d < N) {
            float edv = ed[d * H + hh];
            float acc[8];
#pragma unroll
            for (int i = 0; i < 8; ++i) acc[i] = 0.f;
            float l = 0.f;
            int k = rowptr[d], end = rowptr[d + 1];
            for (; k + 8 <= end; k += 8) {
                int s[8];
#pragma unroll
                for (int j = 0; j < 8; ++j) s[j] = csrc[k + j];
                float e[8];
#pragma unroll
                for (int j = 0; j < 8; ++j) e[j] = es[s[j] * H + hh];
                uint4 u[8];
#pragma unroll
                for (int j = 0; j < 8; ++j)
                    u[j] = *(const uint4*)(h + (size_t)s[j] * D + c);
#pragma unroll
                for (int j = 0; j < 8; ++j) {
                    float w = __expf(lrelu(e[j] + edv));
                    l += w;
                    const __half2* hp = (const __half2*)&u[j];
#pragma unroll
                    for (int i = 0; i < 4; ++i) {
                        float2 f = __half22float2(hp[i]);
                        acc[2 * i] += w * f.x;
                        acc[2 * i + 1] += w * f.y;
                    }
                }
            }
            for (; k + 4 <= end; k += 4) {
                int s[4];
#pragma unroll
                for (int j = 0; j < 4; ++j) s[j] = csrc[k + j];
                float e[4];
#pragma unroll
                for (int j = 0; j < 4; ++j) e[j] = es[s[j] * H + hh];
                uint4 u[4];
#pragma unroll
                for (int j = 0; j < 4; ++j)
                    u[j] = *(const uint4*)(h + (size_t)s[j] * D + c);
#pragma unroll
                for (int j = 0; j < 4; ++j) {
                    float w = __expf(lrelu(e[j] + edv));
                    l += w;
                    const __half2* hp = (const __half2*)&u[j];
#pragma unroll
                    for (int i = 0; i < 4; ++i) {
                        float2 f = __half22float2(hp[i]);
                        acc[2 * i] += w * f.x;
                        acc[2 * i + 1] += w * f.y;
                    }
                }
            }
            for (; k < end; ++k) {
                int s = csrc[k];
                float w = __expf(lrelu(es[s * H + hh] + edv));
                uint4 u = *(const uint4*)(h + (size_t)s * D + c);
                l += w;
                const __half2* hp = (const __half2*)&u;
#pragma unroll
                for (int i = 0; i < 4; ++i) {
                    float2 f = __half22float2(hp[i]);
                    acc[2 * i] += w * f.x;
                    acc[2 * i + 1] += w * f.y;
                }
            }
            float rl = 1.f / (l + 1e-16f);
            float4 b0 = *(const float4*)(bias + c);
            float4 b1 = *(const float4*)(bias + c + 4);
            float v[8];
            v[0] = acc[0] * rl + b0.x; v[1] = acc[1] * rl + b0.y;
            v[2] = acc[2] * rl + b0.z; v[3] = acc[3] * rl + b0.w;
            v[4] = acc[4] * rl + b1.x; v[5] = acc[5] * rl + b1.y;
            v[6] = acc[6] * rl + b1.z; v[7] = acc[7] * rl + b1.w;
            float sm = 0.f, ssum = 0.f;
#pragma unroll
            for (int i = 0; i < 8; ++i) { sm += v[i]; ssum += v[i] * v[i]; }
#pragma unroll
            for (int off = 1; off <= 8; off <<= 1) {  // 16-lane group reduce
                sm += __shfl_xor(sm, off);
                ssum += __shfl_xor(ssum, off);
            }
            float mean = sm / D;
            float var = ssum / D - mean * mean;
            float rstd = rsqrtf(var + 1e-5f);
            float4 g0 = *(const float4*)(gam + c);
            float4 g1 = *(const float4*)(gam + c + 4);
            float4 t0 = *(const float4*)(bet + c);
            float4 t1 = *(const float4*)(bet + c + 4);
            float gv[8] = {g0.x, g0.y, g0.z, g0.w, g1.x, g1.y, g1.z, g1.w};
            float tv[8] = {t0.x, t0.y, t0.z, t0.w, t1.x, t1.y, t1.z, t1.w};
            __half2 p[4];
#pragma unroll
            for (int i = 0; i < 4; ++i) {
                float o0 = (v[2 * i] - mean) * rstd * gv[2 * i] + tv[2 * i];
                float o1 = (v[2 * i + 1] - mean) * rstd * gv[2 * i + 1] +
                           tv[2 * i + 1];
                o0 = o0 > 0.f ? o0 : expm1f(o0);
                o1 = o1 > 0.f ? o1 : expm1f(o1);
                p[i] = __floats2half2_rn(o0, o1);
            }
            uint4 uo;
            uo.x = *(unsigned*)&p[0];
            uo.y = *(unsigned*)&p[1];
            uo.z = *(unsigned*)&p[2];
            uo.w = *(unsigned*)&p[3];
            *(uint4*)&lds[r][c] = uo;
        } else {
            uint4 z = {0u, 0u, 0u, 0u};
            *(uint4*)&lds[r][c] = z;
        }
    }
    __syncthreads();
    // -------- phase 2: two 16-row A-tiles + attn epilogue ---------------
    int wave = tid >> 6, lane = tid & 63;
    int quad = lane >> 4, c15 = lane & 15;
    int t0 = (NT == 8) ? 2 * wave : 0;
#pragma unroll
    for (int at = 0; at < 2; ++at) {
        bool act = (NT == 8) || (wave == at);
        if (act) {
            int row0 = blockIdx.x * 32 + at * 16;
            f32x4 a0c, a1c;
            a0c[0] = 0.f; a0c[1] = 0.f; a0c[2] = 0.f; a0c[3] = 0.f;
            a1c = a0c;
#pragma unroll
            for (int ks = 0; ks < NK; ++ks) {
                f16x8 a = *(f16x8*)&lds[at * 16 + c15][quad * 8 + ks * 32];
                f16x8 b0 = *(const f16x8*)(Whf +
                            (size_t)((t0 * NK + ks) * 64 + lane) * 8);
                f16x8 b1 = *(const f16x8*)(Whf +
                            (size_t)(((t0 + 1) * NK + ks) * 64 + lane) * 8);
                a0c = __builtin_amdgcn_mfma_f32_16x16x32_f16(a, b0, a0c,
                                                             0, 0, 0);
                a1c = __builtin_amdgcn_mfma_f32_16x16x32_f16(a, b1, a1c,
                                                             0, 0, 0);
            }
            // store Y (row = quad*4+rr, col = t*16+c15)
#pragma unroll
            for (int rr = 0; rr < 4; ++rr) {
                int row = row0 + quad * 4 + rr;
                if (row < N) {
                    Y[(size_t)row * NOUT + t0 * 16 + c15] = (__half)a0c[rr];
                    Y[(size_t)row * NOUT + (t0 + 1) * 16 + c15] =
                        (__half)a1c[rr];
                }
            }
            // attention epilogue for head hd = t0/2
            int hd = t0 >> 1;
            float as0 = a_src[t0 * 16 + c15];
            float as1 = a_src[(t0 + 1) * 16 + c15];
            float ad0 = a_dst[t0 * 16 + c15];
            float ad1 = a_dst[(t0 + 1) * 16 + c15];
#pragma unroll
            for (int rr = 0; rr < 4; ++rr) {
                float s = a0c[rr] * as0 + a1c[rr] * as1;
                float dd = a0c[rr] * ad0 + a1c[rr] * ad1;
#pragma unroll
                for (int off = 8; off >= 1; off >>= 1) {
                    s += __shfl_xor(s, off);
                    dd += __shfl_xor(dd, off);
                }
                int row = row0 + quad * 4 + rr;
                if (row < N) {
                    if (c15 == 0) es_o[row * HH + hd] = s;
                    if (c15 == 1) ed_o[row * HH + hd] = dd;
                }
            }
        }
    }
}

// ---------- layer 3: aggregate (D=32) + bias + LN + ELU + pool --------------
// 8 dsts per 64-lane wave: 8 lanes per dst (cl = lane&7), 4 channels each via
// uint2 (8 B) loads. 32 dsts per block.
__global__ __launch_bounds__(256) void aggr_ln32_pool_kernel(
    const int* __restrict__ rowptr, const int* __restrict__ csrc,
    const __half* __restrict__ h, const float* __restrict__ es,
    const float* __restrict__ ed, const float* __restrict__ bias,
    const float* __restrict__ gam, const float* __restrict__ bet,
    const int* __restrict__ batch, float* __restrict__ psum,
    unsigned* __restrict__ pmax, float* __restrict__ cnt, int N) {
    constexpr int D = 32;
    __shared__ float lsum[2][32];
    __shared__ unsigned lmax[2][32];
    __shared__ float lcnt[2];
    __shared__ int g0s;
    int tid = threadIdx.x;
    int d = (blockIdx.x * 256 + tid) >> 3;   // 8-lane group per dst
    int cl = tid & 7;
    int c = cl * 4;
    int dbase = blockIdx.x * 32;  // first node of this block
    if (tid < 64) {
        lsum[tid >> 5][tid & 31] = 0.f;
        lmax[tid >> 5][tid & 31] = 0u;
    }
    if (tid < 2) lcnt[tid] = 0.f;
    if (tid == 0) g0s = batch[dbase < N ? dbase : (N - 1)];
    __syncthreads();
    int g0 = g0s;
    if (d < N) {
        float edv = ed[d];
        float acc[4] = {0.f, 0.f, 0.f, 0.f};
        float l = 0.f;
        int k = rowptr[d], end = rowptr[d + 1];
        for (; k + 8 <= end; k += 8) {
            int s[8];
#pragma unroll
            for (int j = 0; j < 8; ++j) s[j] = csrc[k + j];
            float e[8];
#pragma unroll
            for (int j = 0; j < 8; ++j) e[j] = es[s[j]];
            uint2 u[8];
#pragma unroll
            for (int j = 0; j < 8; ++j)
                u[j] = *(const uint2*)(h + (size_t)s[j] * D + c);
#pragma unroll
            for (int j = 0; j < 8; ++j) {
                float w = __expf(lrelu(e[j] + edv));
                l += w;
                float2 f0 = __half22float2(*(__half2*)&u[j].x);
                float2 f1 = __half22float2(*(__half2*)&u[j].y);
                acc[0] += w * f0.x; acc[1] += w * f0.y;
                acc[2] += w * f1.x; acc[3] += w * f1.y;
            }
        }
        for (; k + 4 <= end; k += 4) {
            int s[4];
#pragma unroll
            for (int j = 0; j < 4; ++j) s[j] = csrc[k + j];
            float e[4];
#pragma unroll
            for (int j = 0; j < 4; ++j) e[j] = es[s[j]];
            uint2 u[4];
#pragma unroll
            for (int j = 0; j < 4; ++j)
                u[j] = *(const uint2*)(h + (size_t)s[j] * D + c);
#pragma unroll
            for (int j = 0; j < 4; ++j) {
                float w = __expf(lrelu(e[j] + edv));
                l += w;
                float2 f0 = __half22float2(*(__half2*)&u[j].x);
                float2 f1 = __half22float2(*(__half2*)&u[j].y);
                acc[0] += w * f0.x; acc[1] += w * f0.y;
                acc[2] += w * f1.x; acc[3] += w * f1.y;
            }
        }
        for (; k < end; ++k) {
            int s = csrc[k];
            float w = __expf(lrelu(es[s] + edv));
            uint2 u = *(const uint2*)(h + (size_t)s * D + c);
            l += w;
            float2 f0 = __half22float2(*(__half2*)&u.x);
            float2 f1 = __half22float2(*(__half2*)&u.y);
            acc[0] += w * f0.x; acc[1] += w * f0.y;
            acc[2] += w * f1.x; acc[3] += w * f1.y;
        }
        float rl = 1.f / (l + 1e-16f);
        float4 b4 = *(const float4*)(bias + c);
        float v0 = acc[0] * rl + b4.x;
        float v1 = acc[1] * rl + b4.y;
        float v2 = acc[2] * rl + b4.z;
        float v3 = acc[3] * rl + b4.w;
        float sm = v0 + v1 + v2 + v3;
        float ssum = v0 * v0 + v1 * v1 + v2 * v2 + v3 * v3;
#pragma unroll
        for (int off = 1; off <= 4; off <<= 1) {
            sm += __shfl_xor(sm, off);
            ssum += __shfl_xor(ssum, off);
        }
        float mean = sm / D;
        float var = ssum / D - mean * mean;
        float rstd = rsqrtf(var + 1e-5f);
        float4 g4 = *(const float4*)(gam + c);
        float4 t4 = *(const float4*)(bet + c);
        float o0 = (v0 - mean) * rstd * g4.x + t4.x;
        float o1 = (v1 - mean) * rstd * g4.y + t4.y;
        float o2 = (v2 - mean) * rstd * g4.z + t4.z;
        float o3 = (v3 - mean) * rstd * g4.w + t4.w;
        o0 = o0 > 0.f ? o0 : expm1f(o0);
        o1 = o1 > 0.f ? o1 : expm1f(o1);
        o2 = o2 > 0.f ? o2 : expm1f(o2);
        o3 = o3 > 0.f ? o3 : expm1f(o3);
        int g = batch[d];
        int goff = g - g0;
        if (goff >= 0 && goff < 2) {
            atomicAdd(&lsum[goff][c + 0], o0);
            atomicAdd(&lsum[goff][c + 1], o1);
            atomicAdd(&lsum[goff][c + 2], o2);
            atomicAdd(&lsum[goff][c + 3], o3);
            atomicMax(&lmax[goff][c + 0], encf(o0));
            atomicMax(&lmax[goff][c + 1], encf(o1));
            atomicMax(&lmax[goff][c + 2], encf(o2));
            atomicMax(&lmax[goff][c + 3], encf(o3));
            if (cl == 0) atomicAdd(&lcnt[goff], 1.0f);
        } else {
            atomicAdd(&psum[g * D + c + 0], o0);
            atomicAdd(&psum[g * D + c + 1], o1);
            atomicAdd(&psum[g * D + c + 2], o2);
            atomicAdd(&psum[g * D + c + 3], o3);
            atomicMax(&pmax[g * D + c + 0], encf(o0));
            atomicMax(&pmax[g * D + c + 1], encf(o1));
            atomicMax(&pmax[g * D + c + 2], encf(o2));
            atomicMax(&pmax[g * D + c + 3], encf(o3));
            if (cl == 0) atomicAdd(&cnt[g], 1.0f);
        }
    }
    __syncthreads();
    if (tid < 64) {
        int go = tid >> 5, cc = tid & 31;
        unsigned m = lmax[go][cc];
        if (m != 0u) {
            int gg = g0 + go;
            atomicAdd(&psum[gg * D + cc], lsum[go][cc]);
            atomicMax(&pmax[gg * D + cc], m);
            if (cc == 0) atomicAdd(&cnt[gg], lcnt[go]);
        }
    }
}

// ---------- fallback aggregation (online softmax, generic shapes) -----------
__global__ __launch_bounds__(256) void aggr_csr_kernel(
    const int* __restrict__ rowptr, const int* __restrict__ csrc,
    const float* __restrict__ h, const float* __restrict__ es,
    const float* __restrict__ ed, float* __restrict__ outp, int N, int H,
    int C) {
    int D = H * C;
    int wave = (blockIdx.x * blockDim.x + threadIdx.x) >> 6;
    int lane = threadIdx.x & 63;
    if (wave >= N) return;
    int d = wave;
    int c0 = lane, c1 = lane + 64;
    bool a0 = c0 < D, a1 = c1 < D;
    int h0 = a0 ? c0 / C : 0;
    int h1 = a1 ? c1 / C : 0;
    float edv0 = a0 ? ed[d * H + h0] : 0.f;
    float edv1 = a1 ? ed[d * H + h1] : 0.f;
    float m0 = -INFINITY, m1 = -INFINITY;
    float l0 = 0.f, l1 = 0.f, acc0 = 0.f, acc1 = 0.f;
    int beg = rowptr[d], end = rowptr[d + 1];
    for (int k = beg; k < end; ++k) {
        int s = csrc[k];
        const float* hp = h + (size_t)s * D;
        if (a0) {
            float v = lrelu(es[s * H + h0] + edv0);
            float nm = fmaxf(m0, v);
            float sc = __expf(m0 - nm);
            float w = __expf(v - nm);
            l0 = l0 * sc + w;
            acc0 = acc0 * sc + w * hp[c0];
            m0 = nm;
        }
        if (a1) {
            float v = lrelu(es[s * H + h1] + edv1);
            float nm = fmaxf(m1, v);
            float sc = __expf(m1 - nm);
            float w = __expf(v - nm);
            l1 = l1 * sc + w;
            acc1 = acc1 * sc + w * hp[c1];
            m1 = nm;
        }
    }
    if (a0) outp[(size_t)d * D + c0] = acc0 / (l0 + 1e-16f);
    if (a1) outp[(size_t)d * D + c1] = acc1 / (l1 + 1e-16f);
}

// ---------- bias + LayerNorm + ELU (fallback path) --------------------------
__global__ __launch_bounds__(64) void ln_elu_kernel(
    const float* __restrict__ in, const float* __restrict__ bias,
    const float* __restrict__ gam, const float* __restrict__ bet,
    float* __restrict__ outp, int D) {
    int n = blockIdx.x;
    int lane = threadIdx.x;  // blockDim = 64
    int c0 = lane, c1 = lane + 64;
    bool a0 = c0 < D, a1 = c1 < D;
    float v0 = 0.f, v1 = 0.f;
    if (a0) v0 = in[(size_t)n * D + c0] + bias[c0];
    if (a1) v1 = in[(size_t)n * D + c1] + bias[c1];
    float s = v0 + v1;
    float ss = v0 * v0 + v1 * v1;
    for (int off = 32; off; off >>= 1) {
        s += __shfl_xor(s, off);
        ss += __shfl_xor(ss, off);
    }
    float mean = s / D;
    float var = ss / D - mean * mean;
    float rstd = rsqrtf(var + 1e-5f);
    if (a0) {
        float o = (v0 - mean) * rstd * gam[c0] + bet[c0];
        outp[(size_t)n * D + c0] = o > 0.f ? o : expm1f(o);
    }
    if (a1) {
        float o = (v1 - mean) * rstd * gam[c1] + bet[c1];
        outp[(size_t)n * D + c1] = o > 0.f ? o : expm1f(o);
    }
}

// ---------- graph pooling (fallback path) -----------------------------------
__global__ __launch_bounds__(256) void pool_kernel(
    const float* __restrict__ h, const int* __restrict__ batch, int N, int C,
    float* __restrict__ psum, unsigned* __restrict__ pmax,
    float* __restrict__ cnt) {
    int idx = blockIdx.x * blockDim.x + threadIdx.x;
    if (idx >= N * C) return;
    int n = idx / C;
    int c = idx - n * C;
    int g = batch[n];
    float v = h[(size_t)n * C + c];
    atomicAdd(&psum[g * C + c], v);
    atomicMax(&pmax[g * C + c], encf(v));
    if (c == 0) atomicAdd(&cnt[g], 1.0f);
}

// ---------- classifier MLP: one block (1 wave) per graph --------------------
__global__ __launch_bounds__(64) void mlp_kernel(
    const float* __restrict__ psum, const unsigned* __restrict__ pmax,
    const float* __restrict__ cnt, const float* __restrict__ cW1,
    const float* __restrict__ cb1, const float* __restrict__ cW2,
    const float* __restrict__ cb2, const float* __restrict__ cW3,
    const float* __restrict__ cb3, float* __restrict__ outp, int C) {
    __shared__ float f[64];
    __shared__ float t1[32];
    __shared__ float t2[16];
    int g = blockIdx.x;
    int t = threadIdx.x;
    float c = fmaxf(cnt[g], 1.0f);
    if (t < C) {
        f[t] = psum[g * C + t] / c;
    } else if (t < 2 * C) {
        unsigned k = pmax[g * C + (t - C)];
        f[t] = (k == 0u) ? -INFINITY : decf(k);
    }
    __syncthreads();
    if (t < 32) {
        float a = cb1[t];
        for (int i = 0; i < 64; ++i) a += f[i] * cW1[t * 64 + i];
        t1[t] = fmaxf(a, 0.f);
    }
    __syncthreads();
    if (t < 16) {
        float a = cb2[t];
        for (int i = 0; i < 32; ++i) a += t1[i] * cW2[t * 32 + i];
        t2[t] = fmaxf(a, 0.f);
    }
    __syncthreads();
    if (t == 0) {
        float a = cb3[0];
        for (int i = 0; i < 16; ++i) a += t2[i] * cW3[i];
        outp[g] = a;
    }
}

// ---------------------------------------------------------------------------
extern "C" void kernel_launch(void* const* d_in, const int* in_sizes, int n_in,
                              void* d_out, int out_size, void* d_ws,
                              size_t ws_size, hipStream_t stream) {
    const float* x = (const float*)d_in[0];
    const int* ei = (const int*)d_in[1];
    const int* batch = (const int*)d_in[2];
    const float* W1 = (const float*)d_in[4];
    const float* as1 = (const float*)d_in[5];
    const float* ad1 = (const float*)d_in[6];
    const float* b1 = (const float*)d_in[7];
    const float* g1 = (const float*)d_in[8];
    const float* be1 = (const float*)d_in[9];
    const float* W2 = (const float*)d_in[10];
    const float* as2 = (const float*)d_in[11];
    const float* ad2 = (const float*)d_in[12];
    const float* b2 = (const float*)d_in[13];
    const float* g2 = (const float*)d_in[14];
    const float* be2 = (const float*)d_in[15];
    const float* W3 = (const float*)d_in[16];
    const float* as3 = (const float*)d_in[17];
    const float* ad3 = (const float*)d_in[18];
    const float* b3 = (const float*)d_in[19];
    const float* g3 = (const float*)d_in[20];
    const float* be3 = (const float*)d_in[21];
    const float* cW1 = (const float*)d_in[22];
    const float* cb1 = (const float*)d_in[23];
    const float* cW2 = (const float*)d_in[24];
    const float* cb2 = (const float*)d_in[25];
    const float* cW3 = (const float*)d_in[26];
    const float* cb3 = (const float*)d_in[27];

    const int N = in_sizes[2];            // 50000
    const int E = in_sizes[1] / 2;        // 800000
    const int F0 = in_sizes[0] / N;       // 32
    const int Hd = in_sizes[19];          // 32 (b3)
    const int H = in_sizes[5] / Hd;       // 4
    const int D = H * Hd;                 // 128
    const int H3 = in_sizes[17] / Hd;     // 1
    const int G = out_size;               // 512
    const int EN = E + N;
    const bool shapes_ok = (F0 == 32 && Hd == 32 && H == 4 && D == 128 &&
                            H3 == 1 && N <= 65536);

    // -------- workspace carve-out (256B aligned) --------
    char* w = (char*)d_ws;
    size_t off = 0;
    auto carve = [&](size_t bytes) -> void* {
        void* p = w + off;
        off = (off + bytes + 255) & ~(size_t)255;
        return p;
    };
    float* Q = (float*)carve((size_t)N * D * 4);      // fallback fp32 staging
    __half* Qh = (__half*)Q;                          // main path fp16 h1/h3
    float* R = (float*)carve((size_t)N * D * 4);      // fallback scratch
    float* P = (float*)carve((size_t)N * D * 4);      // fallback activations
    __half* Ph = (__half*)P;                          // main path fp16 h2
    float* es1 = (float*)carve((size_t)N * H * 4);
    float* ed1 = (float*)carve((size_t)N * H * 4);
    float* es2 = (float*)carve((size_t)N * H * 4);
    float* ed2 = (float*)carve((size_t)N * H * 4);
    int* rowptr = (int*)carve((size_t)(N + 1) * 4);
    int* cursor = (int*)carve((size_t)N * 4);
    int* csrc = (int*)carve((size_t)EN * 4);
    int* bsum = (int*)carve((size_t)CDIV(N, SCAN_BS) * 4);
    const int nblkA = CDIV(E, ATILE);
    int* ghist = (int*)carve((size_t)nblkA * NBUK * 4);
    int* tot = (int*)carve((size_t)NBUK * 4);
    unsigned* ebuf = (unsigned*)carve((size_t)E * 4);
    __half* wh2 = (__half*)carve((size_t)8 * 4 * 64 * 8 * 2);
    __half* wh3 = (__half*)carve((size_t)2 * 4 * 64 * 8 * 2);
    // psum/pmax/cnt carved contiguously (sizes are 256B multiples) so one
    // zero-fill covers all three.
    float* psum = (float*)carve((size_t)G * Hd * 4);
    unsigned* pmax = (unsigned*)carve((size_t)G * Hd * 4);
    float* cnt = (float*)carve((size_t)G * 4);
    (void)ws_size;
    (void)n_in;

    const int BLK = 256;
    const int nb = CDIV(N, SCAN_BS);
    const int poolInts = G * Hd * 2 + G;  // psum + pmax + cnt (ints)

    if (shapes_ok) {
        // ---- bucketed CSR build; binA1 also zero-fills pooling buffers,
        //      runs wh2/wh3 swizzles (10 blocks) AND the full layer-1
        //      GEMM+attn (inline W1->LDS swizzle) as extra block ranges ----
        const int nwp = 10;                  // 2560 threads for wh2+wh3
        const int ngemm1 = CDIV(N, 64);
        binA1_kernel<<<nblkA + nwp + ngemm1, 256, 0, stream>>>(
            ei, E, ghist, (int*)psum, poolInts, W1, W2, W3, wh2, wh3,
            rowptr, N, nblkA, nwp, x, Qh, as1, ad1, es1, ed1);
        binA2a_kernel<<<NBUK, 64, 0, stream>>>(ghist, tot, nblkA);
        binA3_kernel<<<nblkA, 256, 0, stream>>>(ei, E, ghist, tot, ebuf);
        binB_kernel<<<CDIV(N, 128), 256, 0, stream>>>(ebuf, tot, rowptr,
                                                      csrc, N);
        // fused: layer-1 aggregation + LN + ELU -> LDS -> layer-2 GEMM+attn
        // reads h1=Qh,es1/ed1; writes h2=Ph,es2/ed2 (disjoint buffers)
        aggr_gemm_kernel<128, 4><<<CDIV(N, 32), 256, 0, stream>>>(
            rowptr, csrc, Qh, es1, ed1, b1, g1, be1, wh2, Ph, as2, ad2,
            es2, ed2, N);
        // fused: layer-2 aggregation + LN + ELU -> LDS -> layer-3 GEMM+attn
        // reads h2=Ph,es2/ed2; writes h3=Qh (N x 32 fp16), es1/ed1 (N x 1)
        aggr_gemm_kernel<32, 1><<<CDIV(N, 32), 256, 0, stream>>>(
            rowptr, csrc, Ph, es2, ed2, b2, g2, be2, wh3, Qh, as3, ad3,
            es1, ed1, N);
        // layer 3 aggregation (+ fused pooling)
        aggr_ln32_pool_kernel<<<CDIV(N, 32), 256, 0, stream>>>(
            rowptr, csrc, Qh, es1, ed1, b3, g3, be3, batch, psum, pmax,
            cnt, N);
    } else {
        // generic fallback path (all fp32, plain CSR build)
        float* es = es1;
        float* ed = ed1;
        hipMemsetAsync(psum, 0, (size_t)G * Hd * 4, stream);
        hipMemsetAsync(pmax, 0, (size_t)G * Hd * 4, stream);
        hipMemsetAsync(cnt, 0, (size_t)G * 4, stream);
        hipMemsetAsync(cursor, 0, (size_t)N * 4, stream);
        deg_kernel<<<CDIV(E, BLK), BLK, 0, stream>>>(ei, E, cursor);
        scan1_kernel<<<nb, SCAN_BS, 0, stream>>>(cursor, rowptr, bsum, N);
        scan2_kernel<<<1, 64, 0, stream>>>(bsum, nb);
        scan3_kernel<<<nb, SCAN_BS, 0, stream>>>(rowptr, cursor, csrc, bsum, N, EN);
        scatter_kernel<<<CDIV(E, BLK), BLK, 0, stream>>>(ei, E, cursor, csrc);
        gemm_kernel<<<CDIV(N * D, BLK), BLK, 0, stream>>>(x, W1, Q, N, F0, D);
        attn_kernel<<<CDIV(N * H, BLK), BLK, 0, stream>>>(Q, as1, ad1, es, ed, N, H, Hd);
        aggr_csr_kernel<<<CDIV(N, 4), BLK, 0, stream>>>(rowptr, csrc, Q, es, ed, R, N, H, Hd);
        ln_elu_kernel<<<N, 64, 0, stream>>>(R, b1, g1, be1, P, D);
        gemm_kernel<<<CDIV(N * D, BLK), BLK, 0, stream>>>(P, W2, Q, N, D, D);
        attn_kernel<<<CDIV(N * H, BLK), BLK, 0, stream>>>(Q, as2, ad2, es, ed, N, H, Hd);
        aggr_csr_kernel<<<CDIV(N, 4), BLK, 0, stream>>>(rowptr, csrc, Q, es, ed, R, N, H, Hd);
        ln_elu_kernel<<<N, 64, 0, stream>>>(R, b2, g2, be2, P, D);
        gemm_kernel<<<CDIV(N * Hd, BLK), BLK, 0, stream>>>(P, W3, Q, N, D, Hd);
        attn_kernel<<<CDIV(N * H3, BLK), BLK, 0, stream>>>(Q, as3, ad3, es, ed, N, H3, Hd);
        aggr_csr_kernel<<<CDIV(N, 4), BLK, 0, stream>>>(rowptr, csrc, Q, es, ed, R, N, H3, Hd);
        ln_elu_kernel<<<N, 64, 0, stream>>>(R, b3, g3, be3, P, Hd);
        pool_kernel<<<CDIV(N * Hd, BLK), BLK, 0, stream>>>(P, batch, N, Hd, psum, pmax, cnt);
    }

    mlp_kernel<<<G, 64, 0, stream>>>(psum, pmax, cnt, cW1, cb1, cW2, cb2, cW3,
                                     cb3, (float*)d_out, Hd);
}